// Round 5
// baseline (162.512 us; speedup 1.0000x reference)
//
#include <hip/hip_runtime.h>
#include <hip/hip_bf16.h>
#include <cmath>

#define N_NODES 50000
#define N_EDGES 800000
#define CAP 64                                /* bucket cap; Poisson(16) tail @64 ~1e-19 */

#define NBINS 196                             /* bin = dst >> 8 (256 nodes/bin) */
#define BIN_CAP 8192                          /* expected ~4096/bin */
#define CUR_PAD 32                            /* 1 cache line per bin cursor */

#define WCB_ITEMS (144 * 32)                  /* 4608 */
#define WCB_BLOCKS (WCB_ITEMS / 256)          /* 18 exact */
#define WC_ITEMS (192 * 160)                  /* 30720 */
#define WC_BLOCKS (WC_ITEMS / 256)            /* 120 exact */

#define P1_EPT 8                              /* edges per thread, pass 1 */
#define P1_EPB (256 * P1_EPT)                 /* 2048 */
#define P1_BLOCKS ((N_EDGES + P1_EPB - 1) / P1_EPB)  /* 391 */
#define FEAT_BLOCKS ((N_NODES / 16 + 3) / 4)  /* 782 */
#define AGGR_BLOCKS 782                       /* 64 nodes each; 782*64 >= 50000 */

typedef __attribute__((ext_vector_type(8))) short bf16x8;
typedef __attribute__((ext_vector_type(4))) float f32x4;

__device__ inline short bfbits(float x) {
    __hip_bfloat16 t = __float2bfloat16(x);
    return *reinterpret_cast<short*>(&t);
}

__device__ inline unsigned char f32_to_fp8(float x) {
    // OCP e4m3 via v_cvt_pk_fp8_f32; feat |max| ~2.5 << 448, no saturation risk
    return (unsigned char)(__builtin_amdgcn_cvt_pk_fp8_f32(x, x, 0, false) & 0xff);
}

// ---------------------------------------------------------------------------
// K0 (fused prep + zero): blocks [0,18): Wcomb (GAT GEMM B, 144x32).
// blocks [18,138): Wc (GRU GEMM B, 192x160 block-diag).
// block 138: zero the 196 bin cursors (line-padded, stride CUR_PAD).
// ---------------------------------------------------------------------------
__global__ __launch_bounds__(256) void k_prep0(
        const float* __restrict__ Wg, const float* __restrict__ al,
        const float* __restrict__ ar, const float* __restrict__ Wih,
        const float* __restrict__ Whh, __hip_bfloat16* __restrict__ Wcomb,
        __hip_bfloat16* __restrict__ Wc, int* __restrict__ bin_cursor) {
    const int t = threadIdx.x;
    if (blockIdx.x < WCB_BLOCKS) {
        const int idx = blockIdx.x * 256 + t;
        const int row = idx >> 5, k = idx & 31;
        float v = 0.f;
        if (row < 128) {
            v = Wg[k * 128 + row];
        } else if (row < 136) {
            const int hd = (row - 128) & 3;
            const float* a = (row < 132) ? (al + hd * 32) : (ar + hd * 32);
            const float* w = Wg + k * 128 + hd * 32;
#pragma unroll
            for (int f = 0; f < 32; ++f) v = fmaf(w[f], a[f], v);
        }
        Wcomb[idx] = __float2bfloat16(v);
        return;
    }
    if (blockIdx.x < WCB_BLOCKS + WC_BLOCKS) {
        const int idx = (blockIdx.x - WCB_BLOCKS) * 256 + t;
        const int r = idx / 160, k = idx - r * 160;
        float v = 0.f;
        if (r < 96) { if (k < 128) v = Wih[r * 128 + k]; }
        else        { if (k >= 128) v = Whh[(r - 96) * 32 + (k - 128)]; }
        Wc[idx] = __float2bfloat16(v);
        return;
    }
    if (t < NBINS) bin_cursor[t * CUR_PAD] = 0;
}

// ---------------------------------------------------------------------------
// K1 (fused partition-pass1 + feat) — roles dataflow-independent:
// blocks [0,391): partition: int4-vectorized edge loads, LDS-count into 196
//   bins, block scan, one line-padded global atomic per touched bin,
//   contiguous chunk flush. Edge packed 4 B: src | (dst&255) << 16.
// blocks [391,1173): GAT projection via MFMA; feat stored FP8 e4m3.
// ---------------------------------------------------------------------------
__global__ __launch_bounds__(256) void k_part_feat(
        const float* __restrict__ h, const __hip_bfloat16* __restrict__ Wcomb,
        const int* __restrict__ src, const int* __restrict__ dst,
        int* __restrict__ bin_cursor, unsigned* __restrict__ bin_buf,
        unsigned char* __restrict__ feat, float* __restrict__ el,
        float* __restrict__ er) {
    const int t = threadIdx.x;
    if (blockIdx.x < P1_BLOCKS) {
        // ---- partition role ----
        __shared__ int bcnt[256], bofs[256], cur[256], gbase[256];
        __shared__ int wt4[4];
        __shared__ unsigned stage[P1_EPB];    // 8 KB
        bcnt[t] = 0;
        __syncthreads();
        int bn[P1_EPT];
        unsigned pk[P1_EPT];
        const int ebase = blockIdx.x * P1_EPB + t * P1_EPT;  // N_EDGES%8==0: all-or-none
        if (ebase < N_EDGES) {
            int dd[P1_EPT], ss[P1_EPT];
            *(int4*)(dd)     = *(const int4*)(dst + ebase);
            *(int4*)(dd + 4) = *(const int4*)(dst + ebase + 4);
            *(int4*)(ss)     = *(const int4*)(src + ebase);
            *(int4*)(ss + 4) = *(const int4*)(src + ebase + 4);
#pragma unroll
            for (int q = 0; q < P1_EPT; ++q) {
                bn[q] = dd[q] >> 8;
                pk[q] = (unsigned)ss[q] | ((unsigned)(dd[q] & 255) << 16);
                atomicAdd(&bcnt[bn[q]], 1);
            }
        } else {
#pragma unroll
            for (int q = 0; q < P1_EPT; ++q) bn[q] = -1;
        }
        __syncthreads();
        {   // exclusive scan of bcnt[256] (4-wave shfl scan)
            const int wave = t >> 6, lane = t & 63;
            const int vv = bcnt[t];
            int x = vv;
#pragma unroll
            for (int m = 1; m < 64; m <<= 1) {
                const int y = __shfl_up(x, m, 64);
                if (lane >= m) x += y;
            }
            if (lane == 63) wt4[wave] = x;
            __syncthreads();
            int wb = 0;
#pragma unroll
            for (int i = 0; i < 4; ++i) if (i < wave) wb += wt4[i];
            const int off = wb + x - vv;
            bofs[t] = off;
            cur[t] = off;
            gbase[t] = (vv > 0) ? atomicAdd(&bin_cursor[t * CUR_PAD], vv) : 0;
        }
        __syncthreads();
#pragma unroll
        for (int q = 0; q < P1_EPT; ++q)
            if (bn[q] >= 0) stage[atomicAdd(&cur[bn[q]], 1)] = pk[q];
        __syncthreads();
        if (t < NBINS) {                      // flush bin t's contiguous chunk
            const int c = bcnt[t], o = bofs[t], g = gbase[t];
            unsigned* bb = bin_buf + (size_t)t * BIN_CAP;
            for (int j = 0; j < c; ++j) {
                const int gi = g + j;
                if (gi < BIN_CAP) bb[gi] = stage[o + j];
            }
        }
        return;
    }
    // ---- feat role (fp8 output) ----
    __shared__ unsigned char sbuf8[4][16][136];   // 8704 B store staging
    const int lane = t & 63, wave = t >> 6;
    const int li = lane & 15, quad = lane >> 4;
    const int mt = (blockIdx.x - P1_BLOCKS) * 4 + wave;
    if (mt >= N_NODES / 16) return;               // 50000 = 16*3125
    const int m_base = mt * 16;
    bf16x8 a;
    {
        const float4* hp = (const float4*)(h + (size_t)(m_base + li) * 32 + quad * 8);
        const float4 f0 = hp[0], f1 = hp[1];
        a[0] = bfbits(f0.x); a[1] = bfbits(f0.y); a[2] = bfbits(f0.z); a[3] = bfbits(f0.w);
        a[4] = bfbits(f1.x); a[5] = bfbits(f1.y); a[6] = bfbits(f1.z); a[7] = bfbits(f1.w);
    }
    f32x4 acc[9];
#pragma unroll
    for (int j = 0; j < 9; ++j) acc[j] = (f32x4){0.f, 0.f, 0.f, 0.f};
#pragma unroll
    for (int j = 0; j < 9; ++j) {
        const bf16x8 b = *(const bf16x8*)(Wcomb + (size_t)(j * 16 + li) * 32 + quad * 8);
        acc[j] = __builtin_amdgcn_mfma_f32_16x16x32_bf16(a, b, acc[j], 0, 0, 0);
    }
#pragma unroll
    for (int j = 0; j < 8; ++j)
#pragma unroll
        for (int i = 0; i < 4; ++i)
            sbuf8[wave][quad * 4 + i][j * 16 + li] = f32_to_fp8(acc[j][i]);
    __builtin_amdgcn_wave_barrier();
#pragma unroll
    for (int rep = 0; rep < 4; ++rep) {
        const int row = rep * 4 + quad;
        const unsigned long long v = *(const unsigned long long*)(&sbuf8[wave][row][li * 8]);
        *(unsigned long long*)(feat + (size_t)(m_base + row) * 128 + li * 8) = v;
    }
    if (li < 8) {
#pragma unroll
        for (int i = 0; i < 4; ++i) {
            const int m = m_base + quad * 4 + i;
            if (li < 4) el[m * 4 + li] = acc[8][i];
            else        er[m * 4 + (li - 4)] = acc[8][i];
        }
    }
}

// ---------------------------------------------------------------------------
// K2 (fused scat2 + aggr + GRU). R5 = R4 resubmit (infra failure, no verdict).
// Block owns 64 nodes (parent bin = blockIdx>>2, quarter = blockIdx&3):
// reads the parent bin coalesced (uint4), filters to its quarter, builds
// per-node src lists in LDS (ushort[64][64]) — srcs_p/counts round-trip
// (25.6 MB) and the 0.77-occupancy scat2 kernel are gone. Then the R3-proven
// gather (16 waves x 4 nodes) and GRU MFMA on 4 row-tiles (16 waves =
// 4 tiles x 2 colblocks x 2 roles, exact fit). LDS 57.6 KB -> 2 blocks/CU.
// ---------------------------------------------------------------------------
__global__ __launch_bounds__(1024) void k_aggr_gru(
        const int* __restrict__ bin_cursor, const unsigned* __restrict__ bin_buf,
        const unsigned char* __restrict__ feat,
        const float* __restrict__ el, const float* __restrict__ er,
        const float* __restrict__ h, const __hip_bfloat16* __restrict__ Wc,
        const float* __restrict__ bih, const float* __restrict__ bhh,
        float* __restrict__ out) {
    __shared__ unsigned short list[64][CAP];      // 8 KB
    __shared__ int lcnt[64];
    __shared__ __hip_bfloat16 xh_tile[64][160];   // 20 KB
    __shared__ float eel_s[16][64];               // 4 KB
    __shared__ float ex[4][2][3][16][16];         // 24 KB gh exchange
    const int t = threadIdx.x;
    const int wave = t >> 6, lane = t & 63;
    const int pb = blockIdx.x >> 2, sub = blockIdx.x & 3;
    const int nodebase = blockIdx.x * 64;

    if (t < 64) lcnt[t] = 0;
    __syncthreads();

    // ---- stage A: scatter parent bin's quarter into LDS lists ----
    const int cb = min(bin_cursor[pb * CUR_PAD], BIN_CAP);
    const uint4* bb4 = (const uint4*)(bin_buf + (size_t)pb * BIN_CAP);
    for (int i = t * 4; i < cb; i += 4096) {
        const uint4 p4 = bb4[i >> 2];
#pragma unroll
        for (int k = 0; k < 4; ++k) {
            if (i + k < cb) {
                const unsigned p = (&p4.x)[k];
                const int local = (p >> 16) & 255;
                if ((local >> 6) == sub) {
                    const int dl = local & 63;
                    const int pos = atomicAdd(&lcnt[dl], 1);
                    if (pos < CAP) list[dl][pos] = (unsigned short)(p & 0xffff);
                }
            }
        }
    }
    __syncthreads();

    // ---- stage B: aggregate 4 nodes per wave (R3-proven chunk scheme) ----
    const int eh = lane >> 5;          // which edge of the pair
    const int fl = lane & 31;          // feat-dword index: feats 4*fl..4*fl+3
    const int hq = fl >> 3;            // head owning this lane's feats
    float* eel = eel_s[wave];
    for (int u = 0; u < 4; ++u) {
        const int row = wave * 4 + u;
        const int n = nodebase + row;
        const int nvalid = (n < N_NODES);
        const int nc = nvalid ? n : (N_NODES - 1);
        const int cnt = min(lcnt[row], CAP);   // 0 for OOB rows (no edges)
        const unsigned short* sl = list[row];
        const float ern = er[(size_t)nc * 4 + (lane & 3)];
        float a0 = 0.f, a1 = 0.f, a2 = 0.f, a3 = 0.f, psum = 0.f;
        for (int i = 0; i < cnt; i += 16) {
            int sj[8];
#pragma unroll
            for (int j = 0; j < 8; ++j) {
                const int e2 = i + 2 * j + eh;
                sj[j] = sl[e2 < cnt ? e2 : 0];
            }
            unsigned uq[8];
#pragma unroll
            for (int j = 0; j < 8; ++j)
                uq[j] = *(const unsigned*)(feat + (size_t)sj[j] * 128 + fl * 4);
            const int eedge = i + (lane >> 2);
            const int sle = sl[eedge < cnt ? eedge : 0];
            float v = el[(size_t)sle * 4 + (lane & 3)] + ern;
            v = v > 0.f ? v : 0.2f * v;           // leaky_relu(0.2)
            const float wl = (eedge < cnt) ? __expf(v) : 0.f;
            psum += wl;
            eel[lane] = wl;
            __builtin_amdgcn_wave_barrier();
#pragma unroll
            for (int j = 0; j < 8; ++j) {
                const float w = eel[((2 * j + eh) << 2) | hq];
                a0 = fmaf(w, __builtin_amdgcn_cvt_f32_fp8(uq[j], 0), a0);
                a1 = fmaf(w, __builtin_amdgcn_cvt_f32_fp8(uq[j], 1), a1);
                a2 = fmaf(w, __builtin_amdgcn_cvt_f32_fp8(uq[j], 2), a2);
                a3 = fmaf(w, __builtin_amdgcn_cvt_f32_fp8(uq[j], 3), a3);
            }
            __builtin_amdgcn_wave_barrier();      // protect eel reuse next chunk
        }
        // fold edge halves (same features, different edges)
        a0 += __shfl_xor(a0, 32, 64);
        a1 += __shfl_xor(a1, 32, 64);
        a2 += __shfl_xor(a2, 32, 64);
        a3 += __shfl_xor(a3, 32, 64);
        // psum reduce over bits 2..5 -> lane L holds head (L&3) total
#pragma unroll
        for (int m = 4; m < 64; m <<= 1) psum += __shfl_xor(psum, m, 64);
        const float dn = __shfl(psum, hq, 64);    // lane hq's head == hq
        const float inv = (cnt > 0) ? 1.f / dn : 0.f;
        if (lane < 32) {                          // fl == lane: feats 4*lane..+3
            __hip_bfloat162 p0, p1;
            p0.x = __float2bfloat16(a0 * inv); p0.y = __float2bfloat16(a1 * inv);
            p1.x = __float2bfloat16(a2 * inv); p1.y = __float2bfloat16(a3 * inv);
            __hip_bfloat162* xp = (__hip_bfloat162*)&xh_tile[row][0];
            xp[lane * 2]     = p0;
            xp[lane * 2 + 1] = p1;
            xh_tile[row][128 + lane] = nvalid ?
                __float2bfloat16(h[(size_t)n * 32 + lane]) : __float2bfloat16(0.f);
        }
    }
    __syncthreads();

    // ---- stage C: GRU MFMA, 4 row-tiles x 2 colblocks x 2 roles = 16 waves ----
    {
        const int li = lane & 15, quad = lane >> 4;
        const int tt = wave >> 2;          // row tile
        const int cbk = (wave >> 1) & 1;   // output col block
        const int ghrole = wave & 1;       // 0: gi tiles, 1: gh tiles
        bf16x8 a[5];
#pragma unroll
        for (int s = 0; s < 5; ++s)
            a[s] = *(const bf16x8*)((const char*)&xh_tile[tt * 16][0] + li * 320 + s * 64 + quad * 16);
        f32x4 acc[3];
#pragma unroll
        for (int g = 0; g < 3; ++g) {      // g: 0=r, 1=z, 2=n
            acc[g] = (f32x4){0.f, 0.f, 0.f, 0.f};
            const int j = g * 2 + cbk + ghrole * 6;
            const bf16x8* bp = (const bf16x8*)(Wc + (size_t)(j * 16 + li) * 160 + quad * 8);
            acc[g] = __builtin_amdgcn_mfma_f32_16x16x32_bf16(a[0], bp[0],  acc[g], 0, 0, 0);
            acc[g] = __builtin_amdgcn_mfma_f32_16x16x32_bf16(a[1], bp[4],  acc[g], 0, 0, 0);
            acc[g] = __builtin_amdgcn_mfma_f32_16x16x32_bf16(a[2], bp[8],  acc[g], 0, 0, 0);
            acc[g] = __builtin_amdgcn_mfma_f32_16x16x32_bf16(a[3], bp[12], acc[g], 0, 0, 0);
            acc[g] = __builtin_amdgcn_mfma_f32_16x16x32_bf16(a[4], bp[16], acc[g], 0, 0, 0);
        }
        if (ghrole) {
#pragma unroll
            for (int g = 0; g < 3; ++g)
#pragma unroll
                for (int i = 0; i < 4; ++i)
                    ex[tt][cbk][g][quad * 4 + i][li] = acc[g][i];
        }
        __syncthreads();
        if (!ghrole) {
            const int c = cbk * 16 + li;
            const float bir = bih[c],      bhr = bhh[c];
            const float biz = bih[32 + c], bhz = bhh[32 + c];
            const float bin = bih[64 + c], bhn = bhh[64 + c];
#pragma unroll
            for (int i = 0; i < 4; ++i) {
                const int row = quad * 4 + i;
                const int m = nodebase + tt * 16 + row;
                if (m < N_NODES) {
                    const float gr = acc[0][i] + bir + ex[tt][cbk][0][row][li] + bhr;
                    const float gz = acc[1][i] + biz + ex[tt][cbk][1][row][li] + bhz;
                    const float r = 1.f / (1.f + expf(-gr));
                    const float z = 1.f / (1.f + expf(-gz));
                    const float nn = tanhf(acc[2][i] + bin + r * (ex[tt][cbk][2][row][li] + bhn));
                    const float hv = h[(size_t)m * 32 + c];
                    const float hn = (1.f - z) * nn + z * hv;
                    out[(size_t)m * 32 + c] = hn > 0.f ? hn : expm1f(hn);
                }
            }
        }
    }
}

extern "C" void kernel_launch(void* const* d_in, const int* in_sizes, int n_in,
                              void* d_out, int out_size, void* d_ws, size_t ws_size,
                              hipStream_t stream) {
    const float* h   = (const float*)d_in[0];
    const float* Wg  = (const float*)d_in[1];
    const float* al  = (const float*)d_in[2];
    const float* ar  = (const float*)d_in[3];
    const float* Wih = (const float*)d_in[4];
    const float* Whh = (const float*)d_in[5];
    const float* bih = (const float*)d_in[6];
    const float* bhh = (const float*)d_in[7];
    const int* src   = (const int*)d_in[8];
    const int* dst   = (const int*)d_in[9];
    float* out = (float*)d_out;

    // workspace layout (~15 MB)
    float* el = (float*)d_ws;                                 // N*4 f32
    float* er = el + (size_t)N_NODES * 4;                     // N*4 f32
    unsigned char* feat8 = (unsigned char*)(er + (size_t)N_NODES * 4); // N*128 fp8 (6.4 MB)
    __hip_bfloat16* Wc    = (__hip_bfloat16*)(feat8 + (size_t)N_NODES * 128); // 192*160 bf16
    __hip_bfloat16* Wcomb = Wc + 192 * 160;                   // 144*32 bf16
    int* bin_cursor = (int*)(Wcomb + WCB_ITEMS);              // NBINS*CUR_PAD (25 KB)
    unsigned* bin_buf = (unsigned*)(bin_cursor + NBINS * CUR_PAD); // NBINS*BIN_CAP (6.4 MB)

    k_prep0<<<WCB_BLOCKS + WC_BLOCKS + 1, 256, 0, stream>>>(
        Wg, al, ar, Wih, Whh, Wcomb, Wc, bin_cursor);
    k_part_feat<<<P1_BLOCKS + FEAT_BLOCKS, 256, 0, stream>>>(
        h, Wcomb, src, dst, bin_cursor, bin_buf, feat8, el, er);
    k_aggr_gru<<<AGGR_BLOCKS, 1024, 0, stream>>>(
        bin_cursor, bin_buf, feat8, el, er, h, Wc, bih, bhh, out);
}

// Round 6
// 155.993 us; speedup vs baseline: 1.0418x; 1.0418x over previous
//
#include <hip/hip_runtime.h>
#include <hip/hip_bf16.h>
#include <cmath>

#define N_NODES 50000
#define N_EDGES 800000
#define CAP 64                                /* bucket cap; Poisson(16) tail @64 ~1e-19 */

#define NBINS 196                             /* bin = dst >> 8 (256 nodes/bin) */
#define BIN_CAP 8192                          /* expected ~4096/bin */
#define CUR_PAD 32                            /* 1 cache line per bin cursor */

#define WCB_ITEMS (144 * 32)                  /* 4608 */
#define WCB_BLOCKS (WCB_ITEMS / 256)          /* 18 exact */
#define WC_ITEMS (192 * 160)                  /* 30720 */
#define WC_BLOCKS (WC_ITEMS / 256)            /* 120 exact */

#define P1_EPT 8                              /* edges per thread, pass 1 */
#define P1_EPB (256 * P1_EPT)                 /* 2048 */
#define P1_BLOCKS ((N_EDGES + P1_EPB - 1) / P1_EPB)  /* 391 */
#define FEAT_BLOCKS ((N_NODES / 16 + 3) / 4)  /* 782 */

typedef __attribute__((ext_vector_type(8))) short bf16x8;
typedef __attribute__((ext_vector_type(4))) float f32x4;

__device__ inline short bfbits(float x) {
    __hip_bfloat16 t = __float2bfloat16(x);
    return *reinterpret_cast<short*>(&t);
}

__device__ inline unsigned char f32_to_fp8(float x) {
    // OCP e4m3 via v_cvt_pk_fp8_f32; feat |max| ~2.5 << 448, no saturation risk
    return (unsigned char)(__builtin_amdgcn_cvt_pk_fp8_f32(x, x, 0, false) & 0xff);
}

// ---------------------------------------------------------------------------
// K0 (fused prep + zero): blocks [0,18): Wcomb (GAT GEMM B, 144x32).
// blocks [18,138): Wc (GRU GEMM B, 192x160 block-diag).
// block 138: zero the 196 bin cursors (line-padded, stride CUR_PAD).
// ---------------------------------------------------------------------------
__global__ __launch_bounds__(256) void k_prep0(
        const float* __restrict__ Wg, const float* __restrict__ al,
        const float* __restrict__ ar, const float* __restrict__ Wih,
        const float* __restrict__ Whh, __hip_bfloat16* __restrict__ Wcomb,
        __hip_bfloat16* __restrict__ Wc, int* __restrict__ bin_cursor) {
    const int t = threadIdx.x;
    if (blockIdx.x < WCB_BLOCKS) {
        const int idx = blockIdx.x * 256 + t;
        const int row = idx >> 5, k = idx & 31;
        float v = 0.f;
        if (row < 128) {
            v = Wg[k * 128 + row];
        } else if (row < 136) {
            const int hd = (row - 128) & 3;
            const float* a = (row < 132) ? (al + hd * 32) : (ar + hd * 32);
            const float* w = Wg + k * 128 + hd * 32;
#pragma unroll
            for (int f = 0; f < 32; ++f) v = fmaf(w[f], a[f], v);
        }
        Wcomb[idx] = __float2bfloat16(v);
        return;
    }
    if (blockIdx.x < WCB_BLOCKS + WC_BLOCKS) {
        const int idx = (blockIdx.x - WCB_BLOCKS) * 256 + t;
        const int r = idx / 160, k = idx - r * 160;
        float v = 0.f;
        if (r < 96) { if (k < 128) v = Wih[r * 128 + k]; }
        else        { if (k >= 128) v = Whh[(r - 96) * 32 + (k - 128)]; }
        Wc[idx] = __float2bfloat16(v);
        return;
    }
    if (t < NBINS) bin_cursor[t * CUR_PAD] = 0;
}

// ---------------------------------------------------------------------------
// K1a (partition pass 1) — SPLIT from k_part_feat for rocprof attribution
// (R6 diagnostic; body byte-identical to R1's partition role).
// ---------------------------------------------------------------------------
__global__ __launch_bounds__(256) void k_part(
        const int* __restrict__ src, const int* __restrict__ dst,
        int* __restrict__ bin_cursor, unsigned* __restrict__ bin_buf) {
    const int t = threadIdx.x;
    __shared__ int bcnt[256], bofs[256], cur[256], gbase[256];
    __shared__ int wt4[4];
    __shared__ unsigned stage[P1_EPB];    // 8 KB
    bcnt[t] = 0;
    __syncthreads();
    int bn[P1_EPT];
    unsigned pk[P1_EPT];
    const int ebase = blockIdx.x * P1_EPB + t * P1_EPT;  // N_EDGES%8==0: all-or-none
    if (ebase < N_EDGES) {
        int dd[P1_EPT], ss[P1_EPT];
        *(int4*)(dd)     = *(const int4*)(dst + ebase);
        *(int4*)(dd + 4) = *(const int4*)(dst + ebase + 4);
        *(int4*)(ss)     = *(const int4*)(src + ebase);
        *(int4*)(ss + 4) = *(const int4*)(src + ebase + 4);
#pragma unroll
        for (int q = 0; q < P1_EPT; ++q) {
            bn[q] = dd[q] >> 8;
            pk[q] = (unsigned)ss[q] | ((unsigned)(dd[q] & 255) << 16);
            atomicAdd(&bcnt[bn[q]], 1);
        }
    } else {
#pragma unroll
        for (int q = 0; q < P1_EPT; ++q) bn[q] = -1;
    }
    __syncthreads();
    {   // exclusive scan of bcnt[256] (4-wave shfl scan)
        const int wave = t >> 6, lane = t & 63;
        const int vv = bcnt[t];
        int x = vv;
#pragma unroll
        for (int m = 1; m < 64; m <<= 1) {
            const int y = __shfl_up(x, m, 64);
            if (lane >= m) x += y;
        }
        if (lane == 63) wt4[wave] = x;
        __syncthreads();
        int wb = 0;
#pragma unroll
        for (int i = 0; i < 4; ++i) if (i < wave) wb += wt4[i];
        const int off = wb + x - vv;
        bofs[t] = off;
        cur[t] = off;
        gbase[t] = (vv > 0) ? atomicAdd(&bin_cursor[t * CUR_PAD], vv) : 0;
    }
    __syncthreads();
#pragma unroll
    for (int q = 0; q < P1_EPT; ++q)
        if (bn[q] >= 0) stage[atomicAdd(&cur[bn[q]], 1)] = pk[q];
    __syncthreads();
    if (t < NBINS) {                      // flush bin t's contiguous chunk
        const int c = bcnt[t], o = bofs[t], g = gbase[t];
        unsigned* bb = bin_buf + (size_t)t * BIN_CAP;
        for (int j = 0; j < c; ++j) {
            const int gi = g + j;
            if (gi < BIN_CAP) bb[gi] = stage[o + j];
        }
    }
}

// ---------------------------------------------------------------------------
// K1b (GAT projection) — SPLIT from k_part_feat (body identical, blockIdx
// no longer offset). feat stored FP8 e4m3; tile 8 -> el/er f32.
// ---------------------------------------------------------------------------
__global__ __launch_bounds__(256) void k_feat(
        const float* __restrict__ h, const __hip_bfloat16* __restrict__ Wcomb,
        unsigned char* __restrict__ feat, float* __restrict__ el,
        float* __restrict__ er) {
    __shared__ unsigned char sbuf8[4][16][136];   // 8704 B store staging
    const int t = threadIdx.x;
    const int lane = t & 63, wave = t >> 6;
    const int li = lane & 15, quad = lane >> 4;
    const int mt = blockIdx.x * 4 + wave;
    if (mt >= N_NODES / 16) return;               // 50000 = 16*3125
    const int m_base = mt * 16;
    bf16x8 a;
    {
        const float4* hp = (const float4*)(h + (size_t)(m_base + li) * 32 + quad * 8);
        const float4 f0 = hp[0], f1 = hp[1];
        a[0] = bfbits(f0.x); a[1] = bfbits(f0.y); a[2] = bfbits(f0.z); a[3] = bfbits(f0.w);
        a[4] = bfbits(f1.x); a[5] = bfbits(f1.y); a[6] = bfbits(f1.z); a[7] = bfbits(f1.w);
    }
    f32x4 acc[9];
#pragma unroll
    for (int j = 0; j < 9; ++j) acc[j] = (f32x4){0.f, 0.f, 0.f, 0.f};
#pragma unroll
    for (int j = 0; j < 9; ++j) {
        const bf16x8 b = *(const bf16x8*)(Wcomb + (size_t)(j * 16 + li) * 32 + quad * 8);
        acc[j] = __builtin_amdgcn_mfma_f32_16x16x32_bf16(a, b, acc[j], 0, 0, 0);
    }
#pragma unroll
    for (int j = 0; j < 8; ++j)
#pragma unroll
        for (int i = 0; i < 4; ++i)
            sbuf8[wave][quad * 4 + i][j * 16 + li] = f32_to_fp8(acc[j][i]);
    __builtin_amdgcn_wave_barrier();
#pragma unroll
    for (int rep = 0; rep < 4; ++rep) {
        const int row = rep * 4 + quad;
        const unsigned long long v = *(const unsigned long long*)(&sbuf8[wave][row][li * 8]);
        *(unsigned long long*)(feat + (size_t)(m_base + row) * 128 + li * 8) = v;
    }
    if (li < 8) {
#pragma unroll
        for (int i = 0; i < 4; ++i) {
            const int m = m_base + quad * 4 + i;
            if (li < 4) el[m * 4 + li] = acc[8][i];
            else        er[m * 4 + (li - 4)] = acc[8][i];
        }
    }
}

// ---------------------------------------------------------------------------
// K2 (partition pass 2): block b owns nodes [b*256, b*256+256). uint4 reads
// (4 entries/lane); LDS-atomic per-node positions; single-block srcs_p
// locality (R18-proven). Also writes counts.
// ---------------------------------------------------------------------------
__global__ __launch_bounds__(256) void k_scat2(
        const int* __restrict__ bin_cursor, const unsigned* __restrict__ bin_buf,
        int* __restrict__ srcs_p, int* __restrict__ counts) {
    __shared__ int lcnt[256];
    const int t = threadIdx.x;
    const int b = blockIdx.x;
    lcnt[t] = 0;
    __syncthreads();
    const int cb = min(bin_cursor[b * CUR_PAD], BIN_CAP);
    const uint4* bb4 = (const uint4*)(bin_buf + (size_t)b * BIN_CAP);
    for (int i = t * 4; i < cb; i += 1024) {
        const uint4 p4 = bb4[i >> 2];          // i%4==0; reads stay within BIN_CAP
#pragma unroll
        for (int k = 0; k < 4; ++k) {
            if (i + k < cb) {
                const unsigned p = (&p4.x)[k];
                const int dl = p >> 16;
                const int s = p & 0xffff;
                const int pos = atomicAdd(&lcnt[dl], 1);
                if (pos < CAP) srcs_p[(size_t)(b * 256 + dl) * CAP + pos] = s;
            }
        }
    }
    __syncthreads();
    const int node = b * 256 + t;
    if (node < N_NODES) counts[node] = lcnt[t];
}

// ---------------------------------------------------------------------------
// K3 (fused aggr + GRU) — R1 version verbatim (best measured structure):
// 4 nodes/wave, upfront src-list prefetch, pair gather (4 B/lane dword,
// lanes 0-31 edge i / 32-63 edge i+1), cross-half shfl_xor reduce.
// ---------------------------------------------------------------------------
__global__ __launch_bounds__(256) void k_aggr_gru(
        const int* __restrict__ counts, const int* __restrict__ srcs_p,
        const unsigned char* __restrict__ feat,
        const float* __restrict__ el, const float* __restrict__ er,
        const float* __restrict__ h, const __hip_bfloat16* __restrict__ Wc,
        const float* __restrict__ bih, const float* __restrict__ bhh,
        float* __restrict__ out) {
    __shared__ __hip_bfloat16 xh_tile[16][160];   // 5 KB
    __shared__ int   sl_s[4][4][64];              // 4 KB (4 nodes per wave)
    __shared__ float eel_s[4][256];               // 4 KB
    __shared__ float ex[2][3][16][16];            // 6 KB gh exchange
    const int wave = threadIdx.x >> 6;
    const int lane = threadIdx.x & 63;
    float* eel = eel_s[wave];
    const int hs = lane & 3;
    const int eh = lane >> 5;          // which edge of the pair
    const int fl = lane & 31;          // feat-dword index: feats 4*fl..4*fl+3
    const int hq = fl >> 3;            // head owning this lane's feats
    const int mbase = blockIdx.x * 16;

    // ---- phase 1: aggregate 4 nodes per wave ----
    int cnts[4];
#pragma unroll
    for (int u = 0; u < 4; ++u) {      // prefetch all 4 src lists upfront
        const int n = mbase + wave * 4 + u;
        cnts[u] = min(counts[n], CAP);
        if (lane < cnts[u]) sl_s[wave][u][lane] = srcs_p[(size_t)n * CAP + lane];
    }
    __builtin_amdgcn_wave_barrier();
    for (int u = 0; u < 4; ++u) {
        const int row = wave * 4 + u;
        const int n = mbase + row;
        const float ern = er[n * 4 + hs];
        const int cnt = cnts[u];
        const int* sl = sl_s[wave][u];
        float a0 = 0.f, a1 = 0.f, a2 = 0.f, a3 = 0.f, psum = 0.f;
#pragma unroll
        for (int p = 0; p < 4; ++p) {
            const int j = p * 64 + lane;           // j&3 == lane&3
            if (j < cnt * 4) {
                const int s = sl[j >> 2];
                float v = el[s * 4 + hs] + ern;
                v = v > 0.f ? v : 0.2f * v;        // leaky_relu(0.2)
                const float e = __expf(v);
                eel[j] = e;
                psum += e;
            }
        }
        __builtin_amdgcn_wave_barrier();
        int i = 0;
        for (; i + 8 <= cnt; i += 8) {
            const int s0 = sl[i + eh],     s1 = sl[i + 2 + eh];
            const int s2 = sl[i + 4 + eh], s3 = sl[i + 6 + eh];
            const unsigned u0 = *(const unsigned*)(feat + (size_t)s0 * 128 + fl * 4);
            const unsigned u1 = *(const unsigned*)(feat + (size_t)s1 * 128 + fl * 4);
            const unsigned u2 = *(const unsigned*)(feat + (size_t)s2 * 128 + fl * 4);
            const unsigned u3 = *(const unsigned*)(feat + (size_t)s3 * 128 + fl * 4);
            const float w0 = eel[(i + eh) * 4 + hq];
            const float w1 = eel[(i + 2 + eh) * 4 + hq];
            const float w2 = eel[(i + 4 + eh) * 4 + hq];
            const float w3 = eel[(i + 6 + eh) * 4 + hq];
            a0 = fmaf(w0, __builtin_amdgcn_cvt_f32_fp8(u0, 0), a0);
            a1 = fmaf(w0, __builtin_amdgcn_cvt_f32_fp8(u0, 1), a1);
            a2 = fmaf(w0, __builtin_amdgcn_cvt_f32_fp8(u0, 2), a2);
            a3 = fmaf(w0, __builtin_amdgcn_cvt_f32_fp8(u0, 3), a3);
            a0 = fmaf(w1, __builtin_amdgcn_cvt_f32_fp8(u1, 0), a0);
            a1 = fmaf(w1, __builtin_amdgcn_cvt_f32_fp8(u1, 1), a1);
            a2 = fmaf(w1, __builtin_amdgcn_cvt_f32_fp8(u1, 2), a2);
            a3 = fmaf(w1, __builtin_amdgcn_cvt_f32_fp8(u1, 3), a3);
            a0 = fmaf(w2, __builtin_amdgcn_cvt_f32_fp8(u2, 0), a0);
            a1 = fmaf(w2, __builtin_amdgcn_cvt_f32_fp8(u2, 1), a1);
            a2 = fmaf(w2, __builtin_amdgcn_cvt_f32_fp8(u2, 2), a2);
            a3 = fmaf(w2, __builtin_amdgcn_cvt_f32_fp8(u2, 3), a3);
            a0 = fmaf(w3, __builtin_amdgcn_cvt_f32_fp8(u3, 0), a0);
            a1 = fmaf(w3, __builtin_amdgcn_cvt_f32_fp8(u3, 1), a1);
            a2 = fmaf(w3, __builtin_amdgcn_cvt_f32_fp8(u3, 2), a2);
            a3 = fmaf(w3, __builtin_amdgcn_cvt_f32_fp8(u3, 3), a3);
        }
        for (; i < cnt; i += 2) {
            const int e2 = i + eh;
            if (e2 < cnt) {
                const int s0 = sl[e2];
                const unsigned u0 = *(const unsigned*)(feat + (size_t)s0 * 128 + fl * 4);
                const float w0 = eel[e2 * 4 + hq];
                a0 = fmaf(w0, __builtin_amdgcn_cvt_f32_fp8(u0, 0), a0);
                a1 = fmaf(w0, __builtin_amdgcn_cvt_f32_fp8(u0, 1), a1);
                a2 = fmaf(w0, __builtin_amdgcn_cvt_f32_fp8(u0, 2), a2);
                a3 = fmaf(w0, __builtin_amdgcn_cvt_f32_fp8(u0, 3), a3);
            }
        }
        __builtin_amdgcn_wave_barrier();
        a0 += __shfl_xor(a0, 32, 64);             // fold edge halves: same feats
        a1 += __shfl_xor(a1, 32, 64);
        a2 += __shfl_xor(a2, 32, 64);
        a3 += __shfl_xor(a3, 32, 64);
#pragma unroll
        for (int m = 4; m < 64; m <<= 1) psum += __shfl_xor(psum, m, 64);
        const float dn = __shfl(psum, hq, 64);    // lane hq holds denom of head hq
        const float inv = (cnt > 0) ? 1.f / dn : 0.f;
        if (lane < 32) {                          // fl == lane: feats 4*lane..+3
            __hip_bfloat162 p0, p1;
            p0.x = __float2bfloat16(a0 * inv); p0.y = __float2bfloat16(a1 * inv);
            p1.x = __float2bfloat16(a2 * inv); p1.y = __float2bfloat16(a3 * inv);
            __hip_bfloat162* xp = (__hip_bfloat162*)&xh_tile[row][0];
            xp[lane * 2]     = p0;
            xp[lane * 2 + 1] = p1;
            xh_tile[row][128 + lane] = __float2bfloat16(h[(size_t)n * 32 + lane]);
        }
    }
    __syncthreads();

    // ---- phase 2: GRU MFMA, 3 tiles per wave, gh exchange via LDS ----
    const int li = lane & 15, quad = lane >> 4;
    const int cb = wave >> 1;          // output col block
    const int ghrole = wave & 1;       // 0: gi tiles, 1: gh tiles
    bf16x8 a[5];
#pragma unroll
    for (int s = 0; s < 5; ++s)
        a[s] = *(const bf16x8*)((const char*)&xh_tile[0][0] + li * 320 + s * 64 + quad * 16);
    f32x4 acc[3];
#pragma unroll
    for (int g = 0; g < 3; ++g) {      // g: 0=r, 1=z, 2=n
        acc[g] = (f32x4){0.f, 0.f, 0.f, 0.f};
        const int j = g * 2 + cb + ghrole * 6;
        const bf16x8* bp = (const bf16x8*)(Wc + (size_t)(j * 16 + li) * 160 + quad * 8);
        acc[g] = __builtin_amdgcn_mfma_f32_16x16x32_bf16(a[0], bp[0],  acc[g], 0, 0, 0);
        acc[g] = __builtin_amdgcn_mfma_f32_16x16x32_bf16(a[1], bp[4],  acc[g], 0, 0, 0);
        acc[g] = __builtin_amdgcn_mfma_f32_16x16x32_bf16(a[2], bp[8],  acc[g], 0, 0, 0);
        acc[g] = __builtin_amdgcn_mfma_f32_16x16x32_bf16(a[3], bp[12], acc[g], 0, 0, 0);
        acc[g] = __builtin_amdgcn_mfma_f32_16x16x32_bf16(a[4], bp[16], acc[g], 0, 0, 0);
    }
    if (ghrole) {
#pragma unroll
        for (int g = 0; g < 3; ++g)
#pragma unroll
            for (int i = 0; i < 4; ++i)
                ex[cb][g][quad * 4 + i][li] = acc[g][i];
    }
    __syncthreads();
    if (!ghrole) {
        const int c = cb * 16 + li;
        const float bir = bih[c],      bhr = bhh[c];
        const float biz = bih[32 + c], bhz = bhh[32 + c];
        const float bin = bih[64 + c], bhn = bhh[64 + c];
#pragma unroll
        for (int i = 0; i < 4; ++i) {
            const int row = quad * 4 + i;
            const int m = mbase + row;
            const float gr = acc[0][i] + bir + ex[cb][0][row][li] + bhr;
            const float gz = acc[1][i] + biz + ex[cb][1][row][li] + bhz;
            const float r = 1.f / (1.f + expf(-gr));
            const float z = 1.f / (1.f + expf(-gz));
            const float nn = tanhf(acc[2][i] + bin + r * (ex[cb][2][row][li] + bhn));
            const float hv = h[(size_t)m * 32 + c];
            const float hn = (1.f - z) * nn + z * hv;
            out[(size_t)m * 32 + c] = hn > 0.f ? hn : expm1f(hn);
        }
    }
}

extern "C" void kernel_launch(void* const* d_in, const int* in_sizes, int n_in,
                              void* d_out, int out_size, void* d_ws, size_t ws_size,
                              hipStream_t stream) {
    const float* h   = (const float*)d_in[0];
    const float* Wg  = (const float*)d_in[1];
    const float* al  = (const float*)d_in[2];
    const float* ar  = (const float*)d_in[3];
    const float* Wih = (const float*)d_in[4];
    const float* Whh = (const float*)d_in[5];
    const float* bih = (const float*)d_in[6];
    const float* bhh = (const float*)d_in[7];
    const int* src   = (const int*)d_in[8];
    const int* dst   = (const int*)d_in[9];
    float* out = (float*)d_out;

    // workspace layout (~27.5 MB)
    float* el = (float*)d_ws;                                 // N*4 f32
    float* er = el + (size_t)N_NODES * 4;                     // N*4 f32
    unsigned char* feat8 = (unsigned char*)(er + (size_t)N_NODES * 4); // N*128 fp8 (6.4 MB)
    __hip_bfloat16* Wc    = (__hip_bfloat16*)(feat8 + (size_t)N_NODES * 128); // 192*160 bf16
    __hip_bfloat16* Wcomb = Wc + 192 * 160;                   // 144*32 bf16
    int* counts  = (int*)(Wcomb + WCB_ITEMS);                 // N
    int* srcs_p  = counts + N_NODES;                          // N*CAP (12.8 MB)
    int* bin_cursor = srcs_p + (size_t)N_NODES * CAP;         // NBINS*CUR_PAD (25 KB)
    unsigned* bin_buf = (unsigned*)(bin_cursor + NBINS * CUR_PAD); // NBINS*BIN_CAP (6.4 MB)

    k_prep0<<<WCB_BLOCKS + WC_BLOCKS + 1, 256, 0, stream>>>(
        Wg, al, ar, Wih, Whh, Wcomb, Wc, bin_cursor);
    k_part<<<P1_BLOCKS, 256, 0, stream>>>(src, dst, bin_cursor, bin_buf);
    k_feat<<<FEAT_BLOCKS, 256, 0, stream>>>(h, Wcomb, feat8, el, er);
    k_scat2<<<NBINS, 256, 0, stream>>>(bin_cursor, bin_buf, srcs_p, counts);
    k_aggr_gru<<<N_NODES / 16, 256, 0, stream>>>(
        counts, srcs_p, feat8, el, er, h, Wc, bih, bhh, out);
}

// Round 7
// 155.579 us; speedup vs baseline: 1.0446x; 1.0027x over previous
//
#include <hip/hip_runtime.h>
#include <hip/hip_bf16.h>
#include <cmath>

#define N_NODES 50000
#define N_EDGES 800000
#define CAP 64                                /* per-node cap; Poisson(16) tail @64 ~1e-19 */

#define NBINS 196                             /* bin = dst >> 8 (256 nodes/bin) */
#define BIN_CAP 8192                          /* expected ~4096/bin */
#define CUR_PAD 32                            /* 1 cache line per bin cursor */

#define WCB_ITEMS (144 * 32)                  /* 4608 */
#define WC_ITEMS (192 * 160)                  /* 30720 */
#define PREP_ITEMS (WCB_ITEMS + WC_ITEMS)     /* 35328 */
#define PREP_BLOCKS ((PREP_ITEMS + 1023) / 1024)  /* 35 */

#define P1_EPT 2                              /* edges per thread (1024-thr blocks) */
#define P1_EPB (1024 * P1_EPT)                /* 2048 */
#define P1_BLOCKS ((N_EDGES + P1_EPB - 1) / P1_EPB)  /* 391 */
#define FEAT_BLOCKS ((N_NODES / 16 + 3) / 4)  /* 782 */
#define AGGR_BLOCKS (N_NODES / 16)            /* 3125 */

typedef __attribute__((ext_vector_type(8))) short bf16x8;
typedef __attribute__((ext_vector_type(4))) float f32x4;

__device__ inline short bfbits(float x) {
    __hip_bfloat16 t = __float2bfloat16(x);
    return *reinterpret_cast<short*>(&t);
}

__device__ inline unsigned char f32_to_fp8(float x) {
    // OCP e4m3 via v_cvt_pk_fp8_f32; feat |max| ~2.5 << 448, no saturation risk
    return (unsigned char)(__builtin_amdgcn_cvt_pk_fp8_f32(x, x, 0, false) & 0xff);
}

// ---------------------------------------------------------------------------
// K1 (fused partition + weight prep), 1024 threads/block.
// blocks [0,391): partition. R7: 16 waves/block (was 4) — part was running at
//   1.5 blocks/CU = 1-2 waves/SIMD with every load/atomic latency exposed.
//   EPT=2: per-thread 2 count-atomics + 2 scatter-atomics (was 8+8).
//   Barriers restructured to block-uniform (scan work on t<256 only).
// blocks [391,426): Wcomb (GAT GEMM B) + Wc (GRU GEMM B) prep.
// Cursor zeroing moved to hipMemsetAsync (prep0 launch eliminated).
// ---------------------------------------------------------------------------
__global__ __launch_bounds__(1024) void k_part_prep(
        const int* __restrict__ src, const int* __restrict__ dst,
        int* __restrict__ bin_cursor, unsigned* __restrict__ bin_buf,
        const float* __restrict__ Wg, const float* __restrict__ al,
        const float* __restrict__ ar, const float* __restrict__ Wih,
        const float* __restrict__ Whh, __hip_bfloat16* __restrict__ Wcomb,
        __hip_bfloat16* __restrict__ Wc) {
    const int t = threadIdx.x;
    if (blockIdx.x >= P1_BLOCKS) {
        // ---- weight prep role ----
        const int idx = (blockIdx.x - P1_BLOCKS) * 1024 + t;
        if (idx < WCB_ITEMS) {
            const int row = idx >> 5, k = idx & 31;
            float v = 0.f;
            if (row < 128) {
                v = Wg[k * 128 + row];
            } else if (row < 136) {
                const int hd = (row - 128) & 3;
                const float* a = (row < 132) ? (al + hd * 32) : (ar + hd * 32);
                const float* w = Wg + k * 128 + hd * 32;
#pragma unroll
                for (int f = 0; f < 32; ++f) v = fmaf(w[f], a[f], v);
            }
            Wcomb[idx] = __float2bfloat16(v);
        } else if (idx < PREP_ITEMS) {
            const int j = idx - WCB_ITEMS;
            const int r = j / 160, k = j - r * 160;
            float v = 0.f;
            if (r < 96) { if (k < 128) v = Wih[r * 128 + k]; }
            else        { if (k >= 128) v = Whh[(r - 96) * 32 + (k - 128)]; }
            Wc[j] = __float2bfloat16(v);
        }
        return;
    }
    // ---- partition role ----
    __shared__ int bcnt[256], bofs[256], cur[256], gbase[256];
    __shared__ int wt4[4];
    __shared__ unsigned stage[P1_EPB];        // 8 KB
    if (t < 256) bcnt[t] = 0;
    __syncthreads();
    int bn0 = -1, bn1 = -1;
    unsigned pk0 = 0, pk1 = 0;
    const int ebase = blockIdx.x * P1_EPB + t * 2;   // N_EDGES even: all-or-none
    if (ebase < N_EDGES) {
        const int2 dd = *(const int2*)(dst + ebase);
        const int2 ss = *(const int2*)(src + ebase);
        bn0 = dd.x >> 8; pk0 = (unsigned)ss.x | ((unsigned)(dd.x & 255) << 16);
        bn1 = dd.y >> 8; pk1 = (unsigned)ss.y | ((unsigned)(dd.y & 255) << 16);
        atomicAdd(&bcnt[bn0], 1);
        atomicAdd(&bcnt[bn1], 1);
    }
    __syncthreads();
    int x = 0, vv = 0;
    if (t < 256) {                            // waves 0-3 fully active: shfl safe
        vv = bcnt[t];
        x = vv;
        const int lane = t & 63;
#pragma unroll
        for (int m = 1; m < 64; m <<= 1) {
            const int y = __shfl_up(x, m, 64);
            if (lane >= m) x += y;
        }
        if (lane == 63) wt4[t >> 6] = x;
    }
    __syncthreads();
    if (t < 256) {
        const int wave4 = t >> 6;
        int wb = 0;
#pragma unroll
        for (int i = 0; i < 4; ++i) if (i < wave4) wb += wt4[i];
        const int off = wb + x - vv;
        bofs[t] = off;
        cur[t] = off;
        gbase[t] = (vv > 0) ? atomicAdd(&bin_cursor[t * CUR_PAD], vv) : 0;
    }
    __syncthreads();
    if (bn0 >= 0) {
        stage[atomicAdd(&cur[bn0], 1)] = pk0;
        stage[atomicAdd(&cur[bn1], 1)] = pk1;
    }
    __syncthreads();
    if (t < NBINS) {                          // flush bin t's contiguous chunk
        const int c = bcnt[t], o = bofs[t], g = gbase[t];
        unsigned* bb = bin_buf + (size_t)t * BIN_CAP;
        for (int j = 0; j < c; ++j) {
            const int gi = g + j;
            if (gi < BIN_CAP) bb[gi] = stage[o + j];
        }
    }
}

// ---------------------------------------------------------------------------
// K2 (GAT projection) — unchanged proven body. feat stored FP8 e4m3.
// ---------------------------------------------------------------------------
__global__ __launch_bounds__(256) void k_feat(
        const float* __restrict__ h, const __hip_bfloat16* __restrict__ Wcomb,
        unsigned char* __restrict__ feat, float* __restrict__ el,
        float* __restrict__ er) {
    __shared__ unsigned char sbuf8[4][16][136];   // 8704 B store staging
    const int t = threadIdx.x;
    const int lane = t & 63, wave = t >> 6;
    const int li = lane & 15, quad = lane >> 4;
    const int mt = blockIdx.x * 4 + wave;
    if (mt >= N_NODES / 16) return;               // 50000 = 16*3125
    const int m_base = mt * 16;
    bf16x8 a;
    {
        const float4* hp = (const float4*)(h + (size_t)(m_base + li) * 32 + quad * 8);
        const float4 f0 = hp[0], f1 = hp[1];
        a[0] = bfbits(f0.x); a[1] = bfbits(f0.y); a[2] = bfbits(f0.z); a[3] = bfbits(f0.w);
        a[4] = bfbits(f1.x); a[5] = bfbits(f1.y); a[6] = bfbits(f1.z); a[7] = bfbits(f1.w);
    }
    f32x4 acc[9];
#pragma unroll
    for (int j = 0; j < 9; ++j) acc[j] = (f32x4){0.f, 0.f, 0.f, 0.f};
#pragma unroll
    for (int j = 0; j < 9; ++j) {
        const bf16x8 b = *(const bf16x8*)(Wcomb + (size_t)(j * 16 + li) * 32 + quad * 8);
        acc[j] = __builtin_amdgcn_mfma_f32_16x16x32_bf16(a, b, acc[j], 0, 0, 0);
    }
#pragma unroll
    for (int j = 0; j < 8; ++j)
#pragma unroll
        for (int i = 0; i < 4; ++i)
            sbuf8[wave][quad * 4 + i][j * 16 + li] = f32_to_fp8(acc[j][i]);
    __builtin_amdgcn_wave_barrier();
#pragma unroll
    for (int rep = 0; rep < 4; ++rep) {
        const int row = rep * 4 + quad;
        const unsigned long long v = *(const unsigned long long*)(&sbuf8[wave][row][li * 8]);
        *(unsigned long long*)(feat + (size_t)(m_base + row) * 128 + li * 8) = v;
    }
    if (li < 8) {
#pragma unroll
        for (int i = 0; i < 4; ++i) {
            const int m = m_base + quad * 4 + i;
            if (li < 4) el[m * 4 + li] = acc[8][i];
            else        er[m * 4 + (li - 4)] = acc[8][i];
        }
    }
}

// ---------------------------------------------------------------------------
// K3 (aggr + GRU). R7: stage-A builds this block's 16 src lists directly from
// the parent bin (pb = blockIdx>>4, sixteenth = blockIdx&15): coalesced uint4
// read (1/16-useful, L2/L3-resident), LDS-atomic filter into ushort[16][64].
// k_scat2 + srcs_p/counts round-trip (25.6 MB) eliminated; block stays at the
// proven 16-node/256-thread shape (R5's 64-node variant lost occupancy).
// Phase 1/2 bodies = R1 verbatim (best measured).
// ---------------------------------------------------------------------------
__global__ __launch_bounds__(256) void k_aggr_gru(
        const int* __restrict__ bin_cursor, const unsigned* __restrict__ bin_buf,
        const unsigned char* __restrict__ feat,
        const float* __restrict__ el, const float* __restrict__ er,
        const float* __restrict__ h, const __hip_bfloat16* __restrict__ Wc,
        const float* __restrict__ bih, const float* __restrict__ bhh,
        float* __restrict__ out) {
    __shared__ unsigned short list[16][CAP];      // 2 KB
    __shared__ int lcnt[16];
    __shared__ __hip_bfloat16 xh_tile[16][160];   // 5 KB
    __shared__ float eel_s[4][256];               // 4 KB
    __shared__ float ex[2][3][16][16];            // 6 KB gh exchange
    const int t = threadIdx.x;
    const int wave = t >> 6;
    const int lane = t & 63;
    const int pb = blockIdx.x >> 4, six = blockIdx.x & 15;
    const int mbase = blockIdx.x * 16;

    if (t < 16) lcnt[t] = 0;
    __syncthreads();

    // ---- stage A: filter parent bin into this block's 16 LDS lists ----
    const int cbn = min(bin_cursor[pb * CUR_PAD], BIN_CAP);
    const uint4* bb4 = (const uint4*)(bin_buf + (size_t)pb * BIN_CAP);
    for (int i = t * 4; i < cbn; i += 1024) {
        const uint4 p4 = bb4[i >> 2];
#pragma unroll
        for (int k = 0; k < 4; ++k) {
            if (i + k < cbn) {
                const unsigned p = (&p4.x)[k];
                const int local = (p >> 16) & 255;
                if ((local >> 4) == six) {
                    const int dl = local & 15;
                    const int pos = atomicAdd(&lcnt[dl], 1);
                    if (pos < CAP) list[dl][pos] = (unsigned short)(p & 0xffff);
                }
            }
        }
    }
    __syncthreads();

    // ---- phase 1: aggregate 4 nodes per wave (R1-proven) ----
    float* eel = eel_s[wave];
    const int hs = lane & 3;
    const int eh = lane >> 5;          // which edge of the pair
    const int fl = lane & 31;          // feat-dword index: feats 4*fl..4*fl+3
    const int hq = fl >> 3;            // head owning this lane's feats
    for (int u = 0; u < 4; ++u) {
        const int row = wave * 4 + u;
        const int n = mbase + row;
        const float ern = er[n * 4 + hs];
        const int cnt = min(lcnt[row], CAP);
        const unsigned short* sl = list[row];
        float a0 = 0.f, a1 = 0.f, a2 = 0.f, a3 = 0.f, psum = 0.f;
#pragma unroll
        for (int p = 0; p < 4; ++p) {
            const int j = p * 64 + lane;           // j&3 == lane&3
            if (j < cnt * 4) {
                const int s = sl[j >> 2];
                float v = el[s * 4 + hs] + ern;
                v = v > 0.f ? v : 0.2f * v;        // leaky_relu(0.2)
                const float e = __expf(v);
                eel[j] = e;
                psum += e;
            }
        }
        __builtin_amdgcn_wave_barrier();
        int i = 0;
        for (; i + 8 <= cnt; i += 8) {
            const int s0 = sl[i + eh],     s1 = sl[i + 2 + eh];
            const int s2 = sl[i + 4 + eh], s3 = sl[i + 6 + eh];
            const unsigned u0 = *(const unsigned*)(feat + (size_t)s0 * 128 + fl * 4);
            const unsigned u1 = *(const unsigned*)(feat + (size_t)s1 * 128 + fl * 4);
            const unsigned u2 = *(const unsigned*)(feat + (size_t)s2 * 128 + fl * 4);
            const unsigned u3 = *(const unsigned*)(feat + (size_t)s3 * 128 + fl * 4);
            const float w0 = eel[(i + eh) * 4 + hq];
            const float w1 = eel[(i + 2 + eh) * 4 + hq];
            const float w2 = eel[(i + 4 + eh) * 4 + hq];
            const float w3 = eel[(i + 6 + eh) * 4 + hq];
            a0 = fmaf(w0, __builtin_amdgcn_cvt_f32_fp8(u0, 0), a0);
            a1 = fmaf(w0, __builtin_amdgcn_cvt_f32_fp8(u0, 1), a1);
            a2 = fmaf(w0, __builtin_amdgcn_cvt_f32_fp8(u0, 2), a2);
            a3 = fmaf(w0, __builtin_amdgcn_cvt_f32_fp8(u0, 3), a3);
            a0 = fmaf(w1, __builtin_amdgcn_cvt_f32_fp8(u1, 0), a0);
            a1 = fmaf(w1, __builtin_amdgcn_cvt_f32_fp8(u1, 1), a1);
            a2 = fmaf(w1, __builtin_amdgcn_cvt_f32_fp8(u1, 2), a2);
            a3 = fmaf(w1, __builtin_amdgcn_cvt_f32_fp8(u1, 3), a3);
            a0 = fmaf(w2, __builtin_amdgcn_cvt_f32_fp8(u2, 0), a0);
            a1 = fmaf(w2, __builtin_amdgcn_cvt_f32_fp8(u2, 1), a1);
            a2 = fmaf(w2, __builtin_amdgcn_cvt_f32_fp8(u2, 2), a2);
            a3 = fmaf(w2, __builtin_amdgcn_cvt_f32_fp8(u2, 3), a3);
            a0 = fmaf(w3, __builtin_amdgcn_cvt_f32_fp8(u3, 0), a0);
            a1 = fmaf(w3, __builtin_amdgcn_cvt_f32_fp8(u3, 1), a1);
            a2 = fmaf(w3, __builtin_amdgcn_cvt_f32_fp8(u3, 2), a2);
            a3 = fmaf(w3, __builtin_amdgcn_cvt_f32_fp8(u3, 3), a3);
        }
        for (; i < cnt; i += 2) {
            const int e2 = i + eh;
            if (e2 < cnt) {
                const int s0 = sl[e2];
                const unsigned u0 = *(const unsigned*)(feat + (size_t)s0 * 128 + fl * 4);
                const float w0 = eel[e2 * 4 + hq];
                a0 = fmaf(w0, __builtin_amdgcn_cvt_f32_fp8(u0, 0), a0);
                a1 = fmaf(w0, __builtin_amdgcn_cvt_f32_fp8(u0, 1), a1);
                a2 = fmaf(w0, __builtin_amdgcn_cvt_f32_fp8(u0, 2), a2);
                a3 = fmaf(w0, __builtin_amdgcn_cvt_f32_fp8(u0, 3), a3);
            }
        }
        __builtin_amdgcn_wave_barrier();
        a0 += __shfl_xor(a0, 32, 64);             // fold edge halves: same feats
        a1 += __shfl_xor(a1, 32, 64);
        a2 += __shfl_xor(a2, 32, 64);
        a3 += __shfl_xor(a3, 32, 64);
#pragma unroll
        for (int m = 4; m < 64; m <<= 1) psum += __shfl_xor(psum, m, 64);
        const float dn = __shfl(psum, hq, 64);    // lane hq holds denom of head hq
        const float inv = (cnt > 0) ? 1.f / dn : 0.f;
        if (lane < 32) {                          // fl == lane: feats 4*lane..+3
            __hip_bfloat162 p0, p1;
            p0.x = __float2bfloat16(a0 * inv); p0.y = __float2bfloat16(a1 * inv);
            p1.x = __float2bfloat16(a2 * inv); p1.y = __float2bfloat16(a3 * inv);
            __hip_bfloat162* xp = (__hip_bfloat162*)&xh_tile[row][0];
            xp[lane * 2]     = p0;
            xp[lane * 2 + 1] = p1;
            xh_tile[row][128 + lane] = __float2bfloat16(h[(size_t)n * 32 + lane]);
        }
    }
    __syncthreads();

    // ---- phase 2: GRU MFMA, 3 tiles per wave, gh exchange via LDS ----
    const int li = lane & 15, quad = lane >> 4;
    const int cb = wave >> 1;          // output col block
    const int ghrole = wave & 1;       // 0: gi tiles, 1: gh tiles
    bf16x8 a[5];
#pragma unroll
    for (int s = 0; s < 5; ++s)
        a[s] = *(const bf16x8*)((const char*)&xh_tile[0][0] + li * 320 + s * 64 + quad * 16);
    f32x4 acc[3];
#pragma unroll
    for (int g = 0; g < 3; ++g) {      // g: 0=r, 1=z, 2=n
        acc[g] = (f32x4){0.f, 0.f, 0.f, 0.f};
        const int j = g * 2 + cb + ghrole * 6;
        const bf16x8* bp = (const bf16x8*)(Wc + (size_t)(j * 16 + li) * 160 + quad * 8);
        acc[g] = __builtin_amdgcn_mfma_f32_16x16x32_bf16(a[0], bp[0],  acc[g], 0, 0, 0);
        acc[g] = __builtin_amdgcn_mfma_f32_16x16x32_bf16(a[1], bp[4],  acc[g], 0, 0, 0);
        acc[g] = __builtin_amdgcn_mfma_f32_16x16x32_bf16(a[2], bp[8],  acc[g], 0, 0, 0);
        acc[g] = __builtin_amdgcn_mfma_f32_16x16x32_bf16(a[3], bp[12], acc[g], 0, 0, 0);
        acc[g] = __builtin_amdgcn_mfma_f32_16x16x32_bf16(a[4], bp[16], acc[g], 0, 0, 0);
    }
    if (ghrole) {
#pragma unroll
        for (int g = 0; g < 3; ++g)
#pragma unroll
            for (int i = 0; i < 4; ++i)
                ex[cb][g][quad * 4 + i][li] = acc[g][i];
    }
    __syncthreads();
    if (!ghrole) {
        const int c = cb * 16 + li;
        const float bir = bih[c],      bhr = bhh[c];
        const float biz = bih[32 + c], bhz = bhh[32 + c];
        const float bin = bih[64 + c], bhn = bhh[64 + c];
#pragma unroll
        for (int i = 0; i < 4; ++i) {
            const int row = quad * 4 + i;
            const int m = mbase + row;
            const float gr = acc[0][i] + bir + ex[cb][0][row][li] + bhr;
            const float gz = acc[1][i] + biz + ex[cb][1][row][li] + bhz;
            const float r = 1.f / (1.f + expf(-gr));
            const float z = 1.f / (1.f + expf(-gz));
            const float nn = tanhf(acc[2][i] + bin + r * (ex[cb][2][row][li] + bhn));
            const float hv = h[(size_t)m * 32 + c];
            const float hn = (1.f - z) * nn + z * hv;
            out[(size_t)m * 32 + c] = hn > 0.f ? hn : expm1f(hn);
        }
    }
}

extern "C" void kernel_launch(void* const* d_in, const int* in_sizes, int n_in,
                              void* d_out, int out_size, void* d_ws, size_t ws_size,
                              hipStream_t stream) {
    const float* h   = (const float*)d_in[0];
    const float* Wg  = (const float*)d_in[1];
    const float* al  = (const float*)d_in[2];
    const float* ar  = (const float*)d_in[3];
    const float* Wih = (const float*)d_in[4];
    const float* Whh = (const float*)d_in[5];
    const float* bih = (const float*)d_in[6];
    const float* bhh = (const float*)d_in[7];
    const int* src   = (const int*)d_in[8];
    const int* dst   = (const int*)d_in[9];
    float* out = (float*)d_out;

    // workspace layout (~14.5 MB)
    float* el = (float*)d_ws;                                 // N*4 f32
    float* er = el + (size_t)N_NODES * 4;                     // N*4 f32
    unsigned char* feat8 = (unsigned char*)(er + (size_t)N_NODES * 4); // N*128 fp8 (6.4 MB)
    __hip_bfloat16* Wc    = (__hip_bfloat16*)(feat8 + (size_t)N_NODES * 128); // 192*160 bf16
    __hip_bfloat16* Wcomb = Wc + WC_ITEMS;                    // 144*32 bf16
    int* bin_cursor = (int*)(Wcomb + WCB_ITEMS);              // NBINS*CUR_PAD (25 KB)
    unsigned* bin_buf = (unsigned*)(bin_cursor + NBINS * CUR_PAD); // NBINS*BIN_CAP (6.4 MB)

    hipMemsetAsync(bin_cursor, 0, NBINS * CUR_PAD * sizeof(int), stream);
    k_part_prep<<<P1_BLOCKS + PREP_BLOCKS, 1024, 0, stream>>>(
        src, dst, bin_cursor, bin_buf, Wg, al, ar, Wih, Whh, Wcomb, Wc);
    k_feat<<<FEAT_BLOCKS, 256, 0, stream>>>(h, Wcomb, feat8, el, er);
    k_aggr_gru<<<AGGR_BLOCKS, 256, 0, stream>>>(
        bin_cursor, bin_buf, feat8, el, er, h, Wc, bih, bhh, out);
}

// Round 8
// 149.983 us; speedup vs baseline: 1.0835x; 1.0373x over previous
//
#include <hip/hip_runtime.h>
#include <hip/hip_bf16.h>
#include <cmath>

#define N_NODES 50000
#define N_EDGES 800000
#define CAP 64                                /* per-node cap; Poisson(16) tail @64 ~1e-19 */

#define NBINS 196                             /* bin = dst >> 8 (256 nodes/bin) */
#define BIN_CAP 8192                          /* expected ~4096/bin */
#define CUR_PAD 32                            /* 1 cache line per bin cursor */

#define P1_EPT 2                              /* edges per thread (1024-thr blocks) */
#define P1_EPB (1024 * P1_EPT)                /* 2048 */
#define P1_BLOCKS ((N_EDGES + P1_EPB - 1) / P1_EPB)  /* 391 */

#define HB_BLOCKS 98                          /* h->bf16: 100k threads x 16 f32 */
#define ELR_BLOCKS 196                        /* 3125 tiles / 16 waves */
#define WC_BLOCKS 30                          /* 30720 items / 1024 */
#define NB_HB  (P1_BLOCKS)                    /* 391 */
#define NB_ELR (NB_HB + HB_BLOCKS)            /* 489 */
#define NB_WC  (NB_ELR + ELR_BLOCKS)          /* 685 */
#define NB_WGB (NB_WC + WC_BLOCKS)            /* 715 */
#define PREP_TOTAL (NB_WGB + 1)               /* 716 */

#define AGGR_BLOCKS (N_NODES / 16)            /* 3125 */

typedef __attribute__((ext_vector_type(8))) short bf16x8;
typedef __attribute__((ext_vector_type(4))) float f32x4;

__device__ inline short bfbits(float x) {
    __hip_bfloat16 t = __float2bfloat16(x);
    return *reinterpret_cast<short*>(&t);
}
__device__ inline unsigned short bfu16(float x) {
    __hip_bfloat16 t = __float2bfloat16(x);
    return *reinterpret_cast<unsigned short*>(&t);
}

// ---------------------------------------------------------------------------
// K1 (fused partition + all prep), 1024 threads/block.
// [0,391): partition (R7 body, proven).
// [391,489): hb: h -> bf16 copy (3.2 MB table; fits per-XCD L2 for the gather).
// [489,685): elr: el/er = h @ [VL|VR] via one MFMA per 16-node tile
//            (VL[k][h]=sum_f Wg[k][h*32+f]*al[h][f]; VLR computed per block).
// [685,715): Wc (GRU GEMM B, 192x160 block-diag).
// [715]:     Wgb[h*32+f][k] = Wg[k][h*32+f] bf16 (projection B fragments).
// ---------------------------------------------------------------------------
__global__ __launch_bounds__(1024) void k_part_prep(
        const int* __restrict__ src, const int* __restrict__ dst,
        int* __restrict__ bin_cursor, unsigned* __restrict__ bin_buf,
        const float* __restrict__ h, const float* __restrict__ Wg,
        const float* __restrict__ al, const float* __restrict__ ar,
        const float* __restrict__ Wih, const float* __restrict__ Whh,
        unsigned short* __restrict__ hb, float* __restrict__ el,
        float* __restrict__ er, __hip_bfloat16* __restrict__ Wc,
        __hip_bfloat16* __restrict__ Wgb) {
    const int t = threadIdx.x;
    __shared__ union {
        struct {
            int bcnt[256], bofs[256], cur[256], gbase[256];
            int wt4[4];
            unsigned stage[P1_EPB];
        } part;                               // ~12.1 KB
        __hip_bfloat16 vlr[16][32];           // 1 KB
    } sm;

    if (blockIdx.x < P1_BLOCKS) {
        // ---- partition role (R7-proven) ----
        int* bcnt = sm.part.bcnt; int* bofs = sm.part.bofs;
        int* cur = sm.part.cur;   int* gbase = sm.part.gbase;
        int* wt4 = sm.part.wt4;   unsigned* stage = sm.part.stage;
        if (t < 256) bcnt[t] = 0;
        __syncthreads();
        int bn0 = -1, bn1 = -1;
        unsigned pk0 = 0, pk1 = 0;
        const int ebase = blockIdx.x * P1_EPB + t * 2;
        if (ebase < N_EDGES) {
            const int2 dd = *(const int2*)(dst + ebase);
            const int2 ss = *(const int2*)(src + ebase);
            bn0 = dd.x >> 8; pk0 = (unsigned)ss.x | ((unsigned)(dd.x & 255) << 16);
            bn1 = dd.y >> 8; pk1 = (unsigned)ss.y | ((unsigned)(dd.y & 255) << 16);
            atomicAdd(&bcnt[bn0], 1);
            atomicAdd(&bcnt[bn1], 1);
        }
        __syncthreads();
        int x = 0, vv = 0;
        if (t < 256) {
            vv = bcnt[t];
            x = vv;
            const int lane = t & 63;
#pragma unroll
            for (int m = 1; m < 64; m <<= 1) {
                const int y = __shfl_up(x, m, 64);
                if (lane >= m) x += y;
            }
            if (lane == 63) wt4[t >> 6] = x;
        }
        __syncthreads();
        if (t < 256) {
            const int wave4 = t >> 6;
            int wb = 0;
#pragma unroll
            for (int i = 0; i < 4; ++i) if (i < wave4) wb += wt4[i];
            const int off = wb + x - vv;
            bofs[t] = off;
            cur[t] = off;
            gbase[t] = (vv > 0) ? atomicAdd(&bin_cursor[t * CUR_PAD], vv) : 0;
        }
        __syncthreads();
        if (bn0 >= 0) {
            stage[atomicAdd(&cur[bn0], 1)] = pk0;
            stage[atomicAdd(&cur[bn1], 1)] = pk1;
        }
        __syncthreads();
        if (t < NBINS) {
            const int c = bcnt[t], o = bofs[t], g = gbase[t];
            unsigned* bb = bin_buf + (size_t)t * BIN_CAP;
            for (int j = 0; j < c; ++j) {
                const int gi = g + j;
                if (gi < BIN_CAP) bb[gi] = stage[o + j];
            }
        }
        return;
    }
    if (blockIdx.x < NB_ELR) {
        // ---- hb role: h (f32) -> bf16 bits, 16 f32 per thread ----
        const int idx = (blockIdx.x - NB_HB) * 1024 + t;
        const int base = idx * 16;
        if (base < N_NODES * 32) {
            const float4* hp = (const float4*)(h + base);
            const float4 v0 = hp[0], v1 = hp[1], v2 = hp[2], v3 = hp[3];
            unsigned o[8];
            o[0] = (unsigned)bfu16(v0.x) | ((unsigned)bfu16(v0.y) << 16);
            o[1] = (unsigned)bfu16(v0.z) | ((unsigned)bfu16(v0.w) << 16);
            o[2] = (unsigned)bfu16(v1.x) | ((unsigned)bfu16(v1.y) << 16);
            o[3] = (unsigned)bfu16(v1.z) | ((unsigned)bfu16(v1.w) << 16);
            o[4] = (unsigned)bfu16(v2.x) | ((unsigned)bfu16(v2.y) << 16);
            o[5] = (unsigned)bfu16(v2.z) | ((unsigned)bfu16(v2.w) << 16);
            o[6] = (unsigned)bfu16(v3.x) | ((unsigned)bfu16(v3.y) << 16);
            o[7] = (unsigned)bfu16(v3.z) | ((unsigned)bfu16(v3.w) << 16);
            uint4* op = (uint4*)(hb + base);
            op[0] = (uint4){o[0], o[1], o[2], o[3]};
            op[1] = (uint4){o[4], o[5], o[6], o[7]};
        }
        return;
    }
    if (blockIdx.x < NB_WC) {
        // ---- elr role: el/er via MFMA, 16 waves x 16-node tiles ----
        if (t < 512) {
            const int col = t >> 5, k = t & 31;
            float v = 0.f;
            if (col < 8) {
                const int hd = col & 3;
                const float* a = (col < 4) ? (al + hd * 32) : (ar + hd * 32);
                const float* w = Wg + k * 128 + hd * 32;
#pragma unroll
                for (int f = 0; f < 32; ++f) v = fmaf(w[f], a[f], v);
            }
            sm.vlr[col][k] = __float2bfloat16(v);
        }
        __syncthreads();
        const int wave = t >> 6, lane = t & 63;
        const int li = lane & 15, quad = lane >> 4;
        const int mt = (blockIdx.x - NB_ELR) * 16 + wave;
        if (mt >= AGGR_BLOCKS) return;
        const int m_base = mt * 16;
        bf16x8 a;
        {
            const float4* hp = (const float4*)(h + (size_t)(m_base + li) * 32 + quad * 8);
            const float4 f0 = hp[0], f1 = hp[1];
            a[0] = bfbits(f0.x); a[1] = bfbits(f0.y); a[2] = bfbits(f0.z); a[3] = bfbits(f0.w);
            a[4] = bfbits(f1.x); a[5] = bfbits(f1.y); a[6] = bfbits(f1.z); a[7] = bfbits(f1.w);
        }
        const bf16x8 b = *(const bf16x8*)(&sm.vlr[li][0] + quad * 8);
        f32x4 acc = (f32x4){0.f, 0.f, 0.f, 0.f};
        acc = __builtin_amdgcn_mfma_f32_16x16x32_bf16(a, b, acc, 0, 0, 0);
        if (li < 8) {
#pragma unroll
            for (int i = 0; i < 4; ++i) {
                const int m = m_base + quad * 4 + i;
                if (li < 4) el[m * 4 + li] = acc[i];
                else        er[m * 4 + (li - 4)] = acc[i];
            }
        }
        return;
    }
    if (blockIdx.x < NB_WGB) {
        // ---- Wc role (GRU GEMM B, unchanged values) ----
        const int idx = (blockIdx.x - NB_WC) * 1024 + t;
        const int r = idx / 160, k = idx - r * 160;
        float v = 0.f;
        if (r < 96) { if (k < 128) v = Wih[r * 128 + k]; }
        else        { if (k >= 128) v = Whh[(r - 96) * 32 + (k - 128)]; }
        Wc[idx] = __float2bfloat16(v);
        return;
    }
    // ---- Wgb role: projection B, [h*32+f][k] ----
#pragma unroll
    for (int jj = 0; jj < 4; ++jj) {
        const int id = t * 4 + jj;             // 4096 items
        const int k = id & 31, f = (id >> 5) & 31, hd = id >> 10;
        Wgb[id] = __float2bfloat16(Wg[k * 128 + hd * 32 + f]);
    }
}

// ---------------------------------------------------------------------------
// K2 (aggr + project + GRU). R8: aggregation commuted with projection —
// gather bf16 h rows (64 B, 3.2 MB table: fits per-XCD L2) with per-head
// f32 weighted sums, then per-head 16x16x32 MFMA projection (Sn @ Wg_h),
// then GRU phase-2 (verbatim). Stage-A bin filter (R7) kept. eel phase
// (weights) = R1-proven shape. k_feat + feat8 round-trip eliminated.
// ---------------------------------------------------------------------------
__global__ __launch_bounds__(256) void k_aggr_gru(
        const int* __restrict__ bin_cursor, const unsigned* __restrict__ bin_buf,
        const unsigned char* __restrict__ hb,
        const float* __restrict__ el, const float* __restrict__ er,
        const float* __restrict__ h, const __hip_bfloat16* __restrict__ Wc,
        const __hip_bfloat16* __restrict__ Wgb,
        const float* __restrict__ bih, const float* __restrict__ bhh,
        float* __restrict__ out) {
    __shared__ unsigned short list[16][CAP];      // 2 KB
    __shared__ int lcnt[16];
    __shared__ __hip_bfloat16 xh_tile[16][160];   // 5 KB
    __shared__ float eel_s[4][256];               // 4 KB
    __shared__ unsigned Sn[16][64];               // 4 KB: [row][h*16+dw] bf16x2
    __shared__ float ex[2][3][16][16];            // 6 KB gh exchange
    const int t = threadIdx.x;
    const int wave = t >> 6;
    const int lane = t & 63;
    const int pb = blockIdx.x >> 4, six = blockIdx.x & 15;
    const int mbase = blockIdx.x * 16;

    if (t < 16) lcnt[t] = 0;
    __syncthreads();

    // ---- stage A: filter parent bin into this block's 16 LDS lists ----
    const int cbn = min(bin_cursor[pb * CUR_PAD], BIN_CAP);
    const uint4* bb4 = (const uint4*)(bin_buf + (size_t)pb * BIN_CAP);
    for (int i = t * 4; i < cbn; i += 1024) {
        const uint4 p4 = bb4[i >> 2];
#pragma unroll
        for (int k = 0; k < 4; ++k) {
            if (i + k < cbn) {
                const unsigned p = (&p4.x)[k];
                const int local = (p >> 16) & 255;
                if ((local >> 4) == six) {
                    const int dl = local & 15;
                    const int pos = atomicAdd(&lcnt[dl], 1);
                    if (pos < CAP) list[dl][pos] = (unsigned short)(p & 0xffff);
                }
            }
        }
    }
    __syncthreads();

    // ---- phase 1: 4 nodes per wave; weights (R1 eel) + bf16-h gather ----
    float* eel = eel_s[wave];
    const int hs = lane & 3;
    const int eq = lane >> 4;          // edge slot within round (0..3)
    const int dw = lane & 15;          // dword index in 64-B bf16 row
    for (int u = 0; u < 4; ++u) {
        const int row = wave * 4 + u;
        const int n = mbase + row;
        const float ern = er[n * 4 + hs];
        const int cnt = min(lcnt[row], CAP);
        const unsigned short* sl = list[row];
        // zero eel (stale from previous node; gather reads full rounds)
        eel[lane] = 0.f; eel[64 + lane] = 0.f;
        eel[128 + lane] = 0.f; eel[192 + lane] = 0.f;
        __builtin_amdgcn_wave_barrier();
        float psum = 0.f;
#pragma unroll
        for (int p = 0; p < 4; ++p) {
            const int j = p * 64 + lane;           // j&3 == lane&3
            if (j < cnt * 4) {
                const int s = sl[j >> 2];
                float v = el[s * 4 + hs] + ern;
                v = v > 0.f ? v : 0.2f * v;        // leaky_relu(0.2)
                const float e = __expf(v);
                eel[j] = e;
                psum += e;
            }
        }
        __builtin_amdgcn_wave_barrier();
        float a00 = 0.f, a01 = 0.f, a10 = 0.f, a11 = 0.f;
        float a20 = 0.f, a21 = 0.f, a30 = 0.f, a31 = 0.f;
        for (int i = 0; i < cnt; i += 16) {
            int e[4];
#pragma unroll
            for (int j = 0; j < 4; ++j) {
                const int ee = i + j * 4 + eq;
                e[j] = (ee < cnt) ? sl[ee] : 0;    // row 0 safe; weight is 0
            }
            unsigned q[4];
#pragma unroll
            for (int j = 0; j < 4; ++j)
                q[j] = *(const unsigned*)(hb + (size_t)e[j] * 64 + dw * 4);
#pragma unroll
            for (int j = 0; j < 4; ++j) {
                const int ee = i + j * 4 + eq;
                const float lo = __uint_as_float(q[j] << 16);
                const float hi = __uint_as_float(q[j] & 0xffff0000u);
                const float w0 = eel[ee * 4 + 0];
                const float w1 = eel[ee * 4 + 1];
                const float w2 = eel[ee * 4 + 2];
                const float w3 = eel[ee * 4 + 3];
                a00 = fmaf(w0, lo, a00); a01 = fmaf(w0, hi, a01);
                a10 = fmaf(w1, lo, a10); a11 = fmaf(w1, hi, a11);
                a20 = fmaf(w2, lo, a20); a21 = fmaf(w2, hi, a21);
                a30 = fmaf(w3, lo, a30); a31 = fmaf(w3, hi, a31);
            }
        }
        __builtin_amdgcn_wave_barrier();          // eel fully consumed
        // fold the 4 edge-slots (same dw, different eq)
#pragma unroll
        for (int m = 16; m < 64; m <<= 1) {
            a00 += __shfl_xor(a00, m, 64); a01 += __shfl_xor(a01, m, 64);
            a10 += __shfl_xor(a10, m, 64); a11 += __shfl_xor(a11, m, 64);
            a20 += __shfl_xor(a20, m, 64); a21 += __shfl_xor(a21, m, 64);
            a30 += __shfl_xor(a30, m, 64); a31 += __shfl_xor(a31, m, 64);
        }
        // psum: lane L holds head (L&3) total after masks 4..32
#pragma unroll
        for (int m = 4; m < 64; m <<= 1) psum += __shfl_xor(psum, m, 64);
        const float inv0 = (cnt > 0) ? 1.f / __shfl(psum, 0, 64) : 0.f;
        const float inv1 = (cnt > 0) ? 1.f / __shfl(psum, 1, 64) : 0.f;
        const float inv2 = (cnt > 0) ? 1.f / __shfl(psum, 2, 64) : 0.f;
        const float inv3 = (cnt > 0) ? 1.f / __shfl(psum, 3, 64) : 0.f;
        if (lane < 16) {                          // dw == lane: feats 2dw,2dw+1
            Sn[row][0 * 16 + lane] = (unsigned)bfu16(a00 * inv0) | ((unsigned)bfu16(a01 * inv0) << 16);
            Sn[row][1 * 16 + lane] = (unsigned)bfu16(a10 * inv1) | ((unsigned)bfu16(a11 * inv1) << 16);
            Sn[row][2 * 16 + lane] = (unsigned)bfu16(a20 * inv2) | ((unsigned)bfu16(a21 * inv2) << 16);
            Sn[row][3 * 16 + lane] = (unsigned)bfu16(a30 * inv3) | ((unsigned)bfu16(a31 * inv3) << 16);
        }
        if (lane < 32)
            xh_tile[row][128 + lane] = __float2bfloat16(h[(size_t)n * 32 + lane]);
    }
    __syncthreads();

    // ---- phase 1.5: projection MFMA, wave = head ----
    {
        const int li = lane & 15, quad = lane >> 4;
        const int head = wave;
        const __hip_bfloat16* snb = (const __hip_bfloat16*)&Sn[0][0]; // [16][128]
        const bf16x8 aS = *(const bf16x8*)(snb + li * 128 + head * 32 + quad * 8);
        const bf16x8 b0 = *(const bf16x8*)(Wgb + (size_t)(head * 32 + li) * 32 + quad * 8);
        const bf16x8 b1 = *(const bf16x8*)(Wgb + (size_t)(head * 32 + 16 + li) * 32 + quad * 8);
        f32x4 c0 = (f32x4){0.f, 0.f, 0.f, 0.f};
        f32x4 c1 = (f32x4){0.f, 0.f, 0.f, 0.f};
        c0 = __builtin_amdgcn_mfma_f32_16x16x32_bf16(aS, b0, c0, 0, 0, 0);
        c1 = __builtin_amdgcn_mfma_f32_16x16x32_bf16(aS, b1, c1, 0, 0, 0);
#pragma unroll
        for (int i = 0; i < 4; ++i) {
            const int row = quad * 4 + i;
            xh_tile[row][head * 32 + li]      = __float2bfloat16(c0[i]);
            xh_tile[row][head * 32 + 16 + li] = __float2bfloat16(c1[i]);
        }
    }
    __syncthreads();

    // ---- phase 2: GRU MFMA, 3 tiles per wave, gh exchange via LDS ----
    const int li = lane & 15, quad = lane >> 4;
    const int cb = wave >> 1;          // output col block
    const int ghrole = wave & 1;       // 0: gi tiles, 1: gh tiles
    bf16x8 a[5];
#pragma unroll
    for (int s = 0; s < 5; ++s)
        a[s] = *(const bf16x8*)((const char*)&xh_tile[0][0] + li * 320 + s * 64 + quad * 16);
    f32x4 acc[3];
#pragma unroll
    for (int g = 0; g < 3; ++g) {      // g: 0=r, 1=z, 2=n
        acc[g] = (f32x4){0.f, 0.f, 0.f, 0.f};
        const int j = g * 2 + cb + ghrole * 6;
        const bf16x8* bp = (const bf16x8*)(Wc + (size_t)(j * 16 + li) * 160 + quad * 8);
        acc[g] = __builtin_amdgcn_mfma_f32_16x16x32_bf16(a[0], bp[0],  acc[g], 0, 0, 0);
        acc[g] = __builtin_amdgcn_mfma_f32_16x16x32_bf16(a[1], bp[4],  acc[g], 0, 0, 0);
        acc[g] = __builtin_amdgcn_mfma_f32_16x16x32_bf16(a[2], bp[8],  acc[g], 0, 0, 0);
        acc[g] = __builtin_amdgcn_mfma_f32_16x16x32_bf16(a[3], bp[12], acc[g], 0, 0, 0);
        acc[g] = __builtin_amdgcn_mfma_f32_16x16x32_bf16(a[4], bp[16], acc[g], 0, 0, 0);
    }
    if (ghrole) {
#pragma unroll
        for (int g = 0; g < 3; ++g)
#pragma unroll
            for (int i = 0; i < 4; ++i)
                ex[cb][g][quad * 4 + i][li] = acc[g][i];
    }
    __syncthreads();
    if (!ghrole) {
        const int c = cb * 16 + li;
        const float bir = bih[c],      bhr = bhh[c];
        const float biz = bih[32 + c], bhz = bhh[32 + c];
        const float bin = bih[64 + c], bhn = bhh[64 + c];
#pragma unroll
        for (int i = 0; i < 4; ++i) {
            const int row = quad * 4 + i;
            const int m = mbase + row;
            const float gr = acc[0][i] + bir + ex[cb][0][row][li] + bhr;
            const float gz = acc[1][i] + biz + ex[cb][1][row][li] + bhz;
            const float r = 1.f / (1.f + expf(-gr));
            const float z = 1.f / (1.f + expf(-gz));
            const float nn = tanhf(acc[2][i] + bin + r * (ex[cb][2][row][li] + bhn));
            const float hv = h[(size_t)m * 32 + c];
            const float hn = (1.f - z) * nn + z * hv;
            out[(size_t)m * 32 + c] = hn > 0.f ? hn : expm1f(hn);
        }
    }
}

extern "C" void kernel_launch(void* const* d_in, const int* in_sizes, int n_in,
                              void* d_out, int out_size, void* d_ws, size_t ws_size,
                              hipStream_t stream) {
    const float* h   = (const float*)d_in[0];
    const float* Wg  = (const float*)d_in[1];
    const float* al  = (const float*)d_in[2];
    const float* ar  = (const float*)d_in[3];
    const float* Wih = (const float*)d_in[4];
    const float* Whh = (const float*)d_in[5];
    const float* bih = (const float*)d_in[6];
    const float* bhh = (const float*)d_in[7];
    const int* src   = (const int*)d_in[8];
    const int* dst   = (const int*)d_in[9];
    float* out = (float*)d_out;

    // workspace layout (~11.4 MB). hb first: garbage-index reads (zero-weight
    // tail lanes) can reach hb + 4.2 MB, which lands inside bin_buf — safe.
    unsigned short* hb = (unsigned short*)d_ws;               // N*32 bf16 (3.2 MB)
    unsigned* bin_buf = (unsigned*)(hb + (size_t)N_NODES * 32); // NBINS*BIN_CAP (6.4 MB)
    float* el = (float*)(bin_buf + (size_t)NBINS * BIN_CAP);  // N*4 f32
    float* er = el + (size_t)N_NODES * 4;                     // N*4 f32
    __hip_bfloat16* Wc  = (__hip_bfloat16*)(er + (size_t)N_NODES * 4); // 30720 bf16
    __hip_bfloat16* Wgb = Wc + 30720;                         // 4096 bf16
    int* bin_cursor = (int*)(Wgb + 4096);                     // NBINS*CUR_PAD

    hipMemsetAsync(bin_cursor, 0, NBINS * CUR_PAD * sizeof(int), stream);
    k_part_prep<<<PREP_TOTAL, 1024, 0, stream>>>(
        src, dst, bin_cursor, bin_buf, h, Wg, al, ar, Wih, Whh,
        hb, el, er, Wc, Wgb);
    k_aggr_gru<<<AGGR_BLOCKS, 256, 0, stream>>>(
        bin_cursor, bin_buf, (const unsigned char*)hb, el, er, h, Wc, Wgb,
        bih, bhh, out);
}

// Round 9
// 145.618 us; speedup vs baseline: 1.1160x; 1.0300x over previous
//
#include <hip/hip_runtime.h>
#include <hip/hip_bf16.h>
#include <cmath>

#define N_NODES 50000
#define N_EDGES 800000
#define CAP 64                                /* per-node cap; Poisson(16) tail @64 ~1e-19 */

#define NBINS 196                             /* bin = dst >> 8 (256 nodes/bin) */
#define BIN_CAP 8192                          /* expected ~4096/bin */
#define CUR_PAD 32                            /* 1 cache line per bin cursor */

#define P1_EPT 2                              /* edges per thread (1024-thr blocks) */
#define P1_EPB (1024 * P1_EPT)                /* 2048 */
#define P1_BLOCKS ((N_EDGES + P1_EPB - 1) / P1_EPB)  /* 391 */

#define HB_BLOCKS 98                          /* h->bf16: 100k threads x 16 f32 */
#define ELR_BLOCKS 196                        /* 3125 tiles / 16 waves */
#define WC_BLOCKS 30                          /* 30720 items / 1024 */
#define NB_HB  (P1_BLOCKS)                    /* 391 */
#define NB_ELR (NB_HB + HB_BLOCKS)            /* 489 */
#define NB_WC  (NB_ELR + ELR_BLOCKS)          /* 685 */
#define NB_WGB (NB_WC + WC_BLOCKS)            /* 715 */
#define PREP_TOTAL (NB_WGB + 1)               /* 716 */

#define AGGR_BLOCKS (N_NODES / 16)            /* 3125 */

typedef __attribute__((ext_vector_type(8))) short bf16x8;
typedef __attribute__((ext_vector_type(4))) float f32x4;

__device__ inline short bfbits(float x) {
    __hip_bfloat16 t = __float2bfloat16(x);
    return *reinterpret_cast<short*>(&t);
}
__device__ inline unsigned short bfu16(float x) {
    __hip_bfloat16 t = __float2bfloat16(x);
    return *reinterpret_cast<unsigned short*>(&t);
}

// ---------------------------------------------------------------------------
// K1 (fused partition + all prep), 1024 threads/block.
// [0,391): partition. R9: stage entry = src | dst<<16 (both <2^16; bin =
//   entry>>24 for free) -> flush is COOPERATIVE + COALESCED: thread i writes
//   stage[i] to bin_buf[gbase[b] + i - bofs[b]]. The old per-bin serial flush
//   (2048 scattered 4B stores to ~196 lines, ~16x write amplification + RMW)
//   is the suspected ~40 us partition cost.
// [391,489): hb: h -> bf16 (3.2 MB gather table, fits per-XCD L2).
// [489,685): elr: el/er via one MFMA per 16-node tile.
// [685,715): Wc (GRU GEMM B). [715]: Wgb (projection B fragments).
// ---------------------------------------------------------------------------
__global__ __launch_bounds__(1024) void k_part_prep(
        const int* __restrict__ src, const int* __restrict__ dst,
        int* __restrict__ bin_cursor, unsigned* __restrict__ bin_buf,
        const float* __restrict__ h, const float* __restrict__ Wg,
        const float* __restrict__ al, const float* __restrict__ ar,
        const float* __restrict__ Wih, const float* __restrict__ Whh,
        unsigned short* __restrict__ hb, float* __restrict__ el,
        float* __restrict__ er, __hip_bfloat16* __restrict__ Wc,
        __hip_bfloat16* __restrict__ Wgb) {
    const int t = threadIdx.x;
    __shared__ union {
        struct {
            int bcnt[256], bofs[256], cur[256], gbase[256];
            int wt4[4];
            unsigned stage[P1_EPB];
        } part;                               // ~12.1 KB
        __hip_bfloat16 vlr[16][32];           // 1 KB
    } sm;

    if (blockIdx.x < P1_BLOCKS) {
        // ---- partition role ----
        int* bcnt = sm.part.bcnt; int* bofs = sm.part.bofs;
        int* cur = sm.part.cur;   int* gbase = sm.part.gbase;
        int* wt4 = sm.part.wt4;   unsigned* stage = sm.part.stage;
        if (t < 256) bcnt[t] = 0;
        __syncthreads();
        int bn0 = -1, bn1 = -1;
        unsigned pk0 = 0, pk1 = 0;
        const int ebase = blockIdx.x * P1_EPB + t * 2;
        if (ebase < N_EDGES) {
            const int2 dd = *(const int2*)(dst + ebase);
            const int2 ss = *(const int2*)(src + ebase);
            bn0 = dd.x >> 8; pk0 = (unsigned)ss.x | ((unsigned)dd.x << 16);
            bn1 = dd.y >> 8; pk1 = (unsigned)ss.y | ((unsigned)dd.y << 16);
            atomicAdd(&bcnt[bn0], 1);
            atomicAdd(&bcnt[bn1], 1);
        }
        __syncthreads();
        int x = 0, vv = 0;
        if (t < 256) {
            vv = bcnt[t];
            x = vv;
            const int lane = t & 63;
#pragma unroll
            for (int m = 1; m < 64; m <<= 1) {
                const int y = __shfl_up(x, m, 64);
                if (lane >= m) x += y;
            }
            if (lane == 63) wt4[t >> 6] = x;
        }
        __syncthreads();
        if (t < 256) {
            const int wave4 = t >> 6;
            int wb = 0;
#pragma unroll
            for (int i = 0; i < 4; ++i) if (i < wave4) wb += wt4[i];
            const int off = wb + x - vv;
            bofs[t] = off;
            cur[t] = off;
            gbase[t] = (vv > 0) ? atomicAdd(&bin_cursor[t * CUR_PAD], vv) : 0;
        }
        __syncthreads();
        if (bn0 >= 0) {
            stage[atomicAdd(&cur[bn0], 1)] = pk0;
            stage[atomicAdd(&cur[bn1], 1)] = pk1;
        }
        __syncthreads();
        // coalesced cooperative flush
        const int tot = wt4[0] + wt4[1] + wt4[2] + wt4[3];
        for (int i = t; i < tot; i += 1024) {
            const unsigned e = stage[i];
            const int b = e >> 24;                 // dst>>8 (dst<2^16)
            const int gi = gbase[b] + (i - bofs[b]);
            if (gi < BIN_CAP) bin_buf[(size_t)b * BIN_CAP + gi] = e;
        }
        return;
    }
    if (blockIdx.x < NB_ELR) {
        // ---- hb role: h (f32) -> bf16 bits, 16 f32 per thread ----
        const int idx = (blockIdx.x - NB_HB) * 1024 + t;
        const int base = idx * 16;
        if (base < N_NODES * 32) {
            const float4* hp = (const float4*)(h + base);
            const float4 v0 = hp[0], v1 = hp[1], v2 = hp[2], v3 = hp[3];
            unsigned o[8];
            o[0] = (unsigned)bfu16(v0.x) | ((unsigned)bfu16(v0.y) << 16);
            o[1] = (unsigned)bfu16(v0.z) | ((unsigned)bfu16(v0.w) << 16);
            o[2] = (unsigned)bfu16(v1.x) | ((unsigned)bfu16(v1.y) << 16);
            o[3] = (unsigned)bfu16(v1.z) | ((unsigned)bfu16(v1.w) << 16);
            o[4] = (unsigned)bfu16(v2.x) | ((unsigned)bfu16(v2.y) << 16);
            o[5] = (unsigned)bfu16(v2.z) | ((unsigned)bfu16(v2.w) << 16);
            o[6] = (unsigned)bfu16(v3.x) | ((unsigned)bfu16(v3.y) << 16);
            o[7] = (unsigned)bfu16(v3.z) | ((unsigned)bfu16(v3.w) << 16);
            uint4* op = (uint4*)(hb + base);
            op[0] = (uint4){o[0], o[1], o[2], o[3]};
            op[1] = (uint4){o[4], o[5], o[6], o[7]};
        }
        return;
    }
    if (blockIdx.x < NB_WC) {
        // ---- elr role: el/er via MFMA, 16 waves x 16-node tiles ----
        if (t < 512) {
            const int col = t >> 5, k = t & 31;
            float v = 0.f;
            if (col < 8) {
                const int hd = col & 3;
                const float* a = (col < 4) ? (al + hd * 32) : (ar + hd * 32);
                const float* w = Wg + k * 128 + hd * 32;
#pragma unroll
                for (int f = 0; f < 32; ++f) v = fmaf(w[f], a[f], v);
            }
            sm.vlr[col][k] = __float2bfloat16(v);
        }
        __syncthreads();
        const int wave = t >> 6, lane = t & 63;
        const int li = lane & 15, quad = lane >> 4;
        const int mt = (blockIdx.x - NB_ELR) * 16 + wave;
        if (mt >= AGGR_BLOCKS) return;
        const int m_base = mt * 16;
        bf16x8 a;
        {
            const float4* hp = (const float4*)(h + (size_t)(m_base + li) * 32 + quad * 8);
            const float4 f0 = hp[0], f1 = hp[1];
            a[0] = bfbits(f0.x); a[1] = bfbits(f0.y); a[2] = bfbits(f0.z); a[3] = bfbits(f0.w);
            a[4] = bfbits(f1.x); a[5] = bfbits(f1.y); a[6] = bfbits(f1.z); a[7] = bfbits(f1.w);
        }
        const bf16x8 b = *(const bf16x8*)(&sm.vlr[li][0] + quad * 8);
        f32x4 acc = (f32x4){0.f, 0.f, 0.f, 0.f};
        acc = __builtin_amdgcn_mfma_f32_16x16x32_bf16(a, b, acc, 0, 0, 0);
        if (li < 8) {
#pragma unroll
            for (int i = 0; i < 4; ++i) {
                const int m = m_base + quad * 4 + i;
                if (li < 4) el[m * 4 + li] = acc[i];
                else        er[m * 4 + (li - 4)] = acc[i];
            }
        }
        return;
    }
    if (blockIdx.x < NB_WGB) {
        // ---- Wc role (GRU GEMM B, unchanged values) ----
        const int idx = (blockIdx.x - NB_WC) * 1024 + t;
        const int r = idx / 160, k = idx - r * 160;
        float v = 0.f;
        if (r < 96) { if (k < 128) v = Wih[r * 128 + k]; }
        else        { if (k >= 128) v = Whh[(r - 96) * 32 + (k - 128)]; }
        Wc[idx] = __float2bfloat16(v);
        return;
    }
    // ---- Wgb role: projection B, [h*32+f][k] ----
#pragma unroll
    for (int jj = 0; jj < 4; ++jj) {
        const int id = t * 4 + jj;             // 4096 items
        const int k = id & 31, f = (id >> 5) & 31, hd = id >> 10;
        Wgb[id] = __float2bfloat16(Wg[k * 128 + hd * 32 + f]);
    }
}

// ---------------------------------------------------------------------------
// K2 (aggr + project + GRU). R8 structure (bf16-h gather, commuted
// projection). R9 delta: phase-2 epilogue transcendentals -> __expf-based
// sigmoid/tanh/elu (library expf/tanhf/expm1f were ~8-14 insts each;
// tolerance has 2x headroom at absmax 0.0156).
// ---------------------------------------------------------------------------
__global__ __launch_bounds__(256) void k_aggr_gru(
        const int* __restrict__ bin_cursor, const unsigned* __restrict__ bin_buf,
        const unsigned char* __restrict__ hb,
        const float* __restrict__ el, const float* __restrict__ er,
        const float* __restrict__ h, const __hip_bfloat16* __restrict__ Wc,
        const __hip_bfloat16* __restrict__ Wgb,
        const float* __restrict__ bih, const float* __restrict__ bhh,
        float* __restrict__ out) {
    __shared__ unsigned short list[16][CAP];      // 2 KB
    __shared__ int lcnt[16];
    __shared__ __hip_bfloat16 xh_tile[16][160];   // 5 KB
    __shared__ float eel_s[4][256];               // 4 KB
    __shared__ unsigned Sn[16][64];               // 4 KB: [row][h*16+dw] bf16x2
    __shared__ float ex[2][3][16][16];            // 6 KB gh exchange
    const int t = threadIdx.x;
    const int wave = t >> 6;
    const int lane = t & 63;
    const int pb = blockIdx.x >> 4, six = blockIdx.x & 15;
    const int mbase = blockIdx.x * 16;

    if (t < 16) lcnt[t] = 0;
    __syncthreads();

    // ---- stage A: filter parent bin into this block's 16 LDS lists ----
    const int cbn = min(bin_cursor[pb * CUR_PAD], BIN_CAP);
    const uint4* bb4 = (const uint4*)(bin_buf + (size_t)pb * BIN_CAP);
    for (int i = t * 4; i < cbn; i += 1024) {
        const uint4 p4 = bb4[i >> 2];
#pragma unroll
        for (int k = 0; k < 4; ++k) {
            if (i + k < cbn) {
                const unsigned p = (&p4.x)[k];
                const int local = (p >> 16) & 255;
                if ((local >> 4) == six) {
                    const int dl = local & 15;
                    const int pos = atomicAdd(&lcnt[dl], 1);
                    if (pos < CAP) list[dl][pos] = (unsigned short)(p & 0xffff);
                }
            }
        }
    }
    __syncthreads();

    // ---- phase 1: 4 nodes per wave; weights (eel) + bf16-h gather ----
    float* eel = eel_s[wave];
    const int hs = lane & 3;
    const int eq = lane >> 4;          // edge slot within round (0..3)
    const int dw = lane & 15;          // dword index in 64-B bf16 row
    for (int u = 0; u < 4; ++u) {
        const int row = wave * 4 + u;
        const int n = mbase + row;
        const float ern = er[n * 4 + hs];
        const int cnt = min(lcnt[row], CAP);
        const unsigned short* sl = list[row];
        // zero eel (stale from previous node; gather reads full rounds)
        eel[lane] = 0.f; eel[64 + lane] = 0.f;
        eel[128 + lane] = 0.f; eel[192 + lane] = 0.f;
        __builtin_amdgcn_wave_barrier();
        float psum = 0.f;
#pragma unroll
        for (int p = 0; p < 4; ++p) {
            const int j = p * 64 + lane;           // j&3 == lane&3
            if (j < cnt * 4) {
                const int s = sl[j >> 2];
                float v = el[s * 4 + hs] + ern;
                v = v > 0.f ? v : 0.2f * v;        // leaky_relu(0.2)
                const float e = __expf(v);
                eel[j] = e;
                psum += e;
            }
        }
        __builtin_amdgcn_wave_barrier();
        float a00 = 0.f, a01 = 0.f, a10 = 0.f, a11 = 0.f;
        float a20 = 0.f, a21 = 0.f, a30 = 0.f, a31 = 0.f;
        for (int i = 0; i < cnt; i += 16) {
            int e[4];
#pragma unroll
            for (int j = 0; j < 4; ++j) {
                const int ee = i + j * 4 + eq;
                e[j] = (ee < cnt) ? sl[ee] : 0;    // row 0 safe; weight is 0
            }
            unsigned q[4];
#pragma unroll
            for (int j = 0; j < 4; ++j)
                q[j] = *(const unsigned*)(hb + (size_t)e[j] * 64 + dw * 4);
#pragma unroll
            for (int j = 0; j < 4; ++j) {
                const int ee = i + j * 4 + eq;
                const float lo = __uint_as_float(q[j] << 16);
                const float hi = __uint_as_float(q[j] & 0xffff0000u);
                const float w0 = eel[ee * 4 + 0];
                const float w1 = eel[ee * 4 + 1];
                const float w2 = eel[ee * 4 + 2];
                const float w3 = eel[ee * 4 + 3];
                a00 = fmaf(w0, lo, a00); a01 = fmaf(w0, hi, a01);
                a10 = fmaf(w1, lo, a10); a11 = fmaf(w1, hi, a11);
                a20 = fmaf(w2, lo, a20); a21 = fmaf(w2, hi, a21);
                a30 = fmaf(w3, lo, a30); a31 = fmaf(w3, hi, a31);
            }
        }
        __builtin_amdgcn_wave_barrier();          // eel fully consumed
        // fold the 4 edge-slots (same dw, different eq)
#pragma unroll
        for (int m = 16; m < 64; m <<= 1) {
            a00 += __shfl_xor(a00, m, 64); a01 += __shfl_xor(a01, m, 64);
            a10 += __shfl_xor(a10, m, 64); a11 += __shfl_xor(a11, m, 64);
            a20 += __shfl_xor(a20, m, 64); a21 += __shfl_xor(a21, m, 64);
            a30 += __shfl_xor(a30, m, 64); a31 += __shfl_xor(a31, m, 64);
        }
        // psum: lane L holds head (L&3) total after masks 4..32
#pragma unroll
        for (int m = 4; m < 64; m <<= 1) psum += __shfl_xor(psum, m, 64);
        const float inv0 = (cnt > 0) ? 1.f / __shfl(psum, 0, 64) : 0.f;
        const float inv1 = (cnt > 0) ? 1.f / __shfl(psum, 1, 64) : 0.f;
        const float inv2 = (cnt > 0) ? 1.f / __shfl(psum, 2, 64) : 0.f;
        const float inv3 = (cnt > 0) ? 1.f / __shfl(psum, 3, 64) : 0.f;
        if (lane < 16) {                          // dw == lane: feats 2dw,2dw+1
            Sn[row][0 * 16 + lane] = (unsigned)bfu16(a00 * inv0) | ((unsigned)bfu16(a01 * inv0) << 16);
            Sn[row][1 * 16 + lane] = (unsigned)bfu16(a10 * inv1) | ((unsigned)bfu16(a11 * inv1) << 16);
            Sn[row][2 * 16 + lane] = (unsigned)bfu16(a20 * inv2) | ((unsigned)bfu16(a21 * inv2) << 16);
            Sn[row][3 * 16 + lane] = (unsigned)bfu16(a30 * inv3) | ((unsigned)bfu16(a31 * inv3) << 16);
        }
        if (lane < 32)
            xh_tile[row][128 + lane] = __float2bfloat16(h[(size_t)n * 32 + lane]);
    }
    __syncthreads();

    // ---- phase 1.5: projection MFMA, wave = head ----
    {
        const int li = lane & 15, quad = lane >> 4;
        const int head = wave;
        const __hip_bfloat16* snb = (const __hip_bfloat16*)&Sn[0][0]; // [16][128]
        const bf16x8 aS = *(const bf16x8*)(snb + li * 128 + head * 32 + quad * 8);
        const bf16x8 b0 = *(const bf16x8*)(Wgb + (size_t)(head * 32 + li) * 32 + quad * 8);
        const bf16x8 b1 = *(const bf16x8*)(Wgb + (size_t)(head * 32 + 16 + li) * 32 + quad * 8);
        f32x4 c0 = (f32x4){0.f, 0.f, 0.f, 0.f};
        f32x4 c1 = (f32x4){0.f, 0.f, 0.f, 0.f};
        c0 = __builtin_amdgcn_mfma_f32_16x16x32_bf16(aS, b0, c0, 0, 0, 0);
        c1 = __builtin_amdgcn_mfma_f32_16x16x32_bf16(aS, b1, c1, 0, 0, 0);
#pragma unroll
        for (int i = 0; i < 4; ++i) {
            const int row = quad * 4 + i;
            xh_tile[row][head * 32 + li]      = __float2bfloat16(c0[i]);
            xh_tile[row][head * 32 + 16 + li] = __float2bfloat16(c1[i]);
        }
    }
    __syncthreads();

    // ---- phase 2: GRU MFMA, 3 tiles per wave, gh exchange via LDS ----
    const int li = lane & 15, quad = lane >> 4;
    const int cb = wave >> 1;          // output col block
    const int ghrole = wave & 1;       // 0: gi tiles, 1: gh tiles
    bf16x8 a[5];
#pragma unroll
    for (int s = 0; s < 5; ++s)
        a[s] = *(const bf16x8*)((const char*)&xh_tile[0][0] + li * 320 + s * 64 + quad * 16);
    f32x4 acc[3];
#pragma unroll
    for (int g = 0; g < 3; ++g) {      // g: 0=r, 1=z, 2=n
        acc[g] = (f32x4){0.f, 0.f, 0.f, 0.f};
        const int j = g * 2 + cb + ghrole * 6;
        const bf16x8* bp = (const bf16x8*)(Wc + (size_t)(j * 16 + li) * 160 + quad * 8);
        acc[g] = __builtin_amdgcn_mfma_f32_16x16x32_bf16(a[0], bp[0],  acc[g], 0, 0, 0);
        acc[g] = __builtin_amdgcn_mfma_f32_16x16x32_bf16(a[1], bp[4],  acc[g], 0, 0, 0);
        acc[g] = __builtin_amdgcn_mfma_f32_16x16x32_bf16(a[2], bp[8],  acc[g], 0, 0, 0);
        acc[g] = __builtin_amdgcn_mfma_f32_16x16x32_bf16(a[3], bp[12], acc[g], 0, 0, 0);
        acc[g] = __builtin_amdgcn_mfma_f32_16x16x32_bf16(a[4], bp[16], acc[g], 0, 0, 0);
    }
    if (ghrole) {
#pragma unroll
        for (int g = 0; g < 3; ++g)
#pragma unroll
            for (int i = 0; i < 4; ++i)
                ex[cb][g][quad * 4 + i][li] = acc[g][i];
    }
    __syncthreads();
    if (!ghrole) {
        const int c = cb * 16 + li;
        const float bir = bih[c],      bhr = bhh[c];
        const float biz = bih[32 + c], bhz = bhh[32 + c];
        const float bin = bih[64 + c], bhn = bhh[64 + c];
#pragma unroll
        for (int i = 0; i < 4; ++i) {
            const int row = quad * 4 + i;
            const int m = mbase + row;
            const float gr = acc[0][i] + bir + ex[cb][0][row][li] + bhr;
            const float gz = acc[1][i] + biz + ex[cb][1][row][li] + bhz;
            const float r = 1.f / (1.f + __expf(-gr));
            const float z = 1.f / (1.f + __expf(-gz));
            const float tv = acc[2][i] + bin + r * (ex[cb][2][row][li] + bhn);
            const float em = __expf(-2.f * fabsf(tv));
            const float nn = copysignf((1.f - em) / (1.f + em), tv);
            const float hv = h[(size_t)m * 32 + c];
            const float hn = (1.f - z) * nn + z * hv;
            out[(size_t)m * 32 + c] = hn > 0.f ? hn : (__expf(hn) - 1.f);
        }
    }
}

extern "C" void kernel_launch(void* const* d_in, const int* in_sizes, int n_in,
                              void* d_out, int out_size, void* d_ws, size_t ws_size,
                              hipStream_t stream) {
    const float* h   = (const float*)d_in[0];
    const float* Wg  = (const float*)d_in[1];
    const float* al  = (const float*)d_in[2];
    const float* ar  = (const float*)d_in[3];
    const float* Wih = (const float*)d_in[4];
    const float* Whh = (const float*)d_in[5];
    const float* bih = (const float*)d_in[6];
    const float* bhh = (const float*)d_in[7];
    const int* src   = (const int*)d_in[8];
    const int* dst   = (const int*)d_in[9];
    float* out = (float*)d_out;

    // workspace layout (~11.4 MB). hb first: garbage-index reads (zero-weight
    // tail lanes) can reach hb + 4.2 MB, which lands inside bin_buf — safe.
    unsigned short* hb = (unsigned short*)d_ws;               // N*32 bf16 (3.2 MB)
    unsigned* bin_buf = (unsigned*)(hb + (size_t)N_NODES * 32); // NBINS*BIN_CAP (6.4 MB)
    float* el = (float*)(bin_buf + (size_t)NBINS * BIN_CAP);  // N*4 f32
    float* er = el + (size_t)N_NODES * 4;                     // N*4 f32
    __hip_bfloat16* Wc  = (__hip_bfloat16*)(er + (size_t)N_NODES * 4); // 30720 bf16
    __hip_bfloat16* Wgb = Wc + 30720;                         // 4096 bf16
    int* bin_cursor = (int*)(Wgb + 4096);                     // NBINS*CUR_PAD

    hipMemsetAsync(bin_cursor, 0, NBINS * CUR_PAD * sizeof(int), stream);
    k_part_prep<<<PREP_TOTAL, 1024, 0, stream>>>(
        src, dst, bin_cursor, bin_buf, h, Wg, al, ar, Wih, Whh,
        hb, el, er, Wc, Wgb);
    k_aggr_gru<<<AGGR_BLOCKS, 256, 0, stream>>>(
        bin_cursor, bin_buf, (const unsigned char*)hb, el, er, h, Wc, Wgb,
        bih, bhh, out);
}

// Round 10
// 142.129 us; speedup vs baseline: 1.1434x; 1.0245x over previous
//
#include <hip/hip_runtime.h>
#include <hip/hip_bf16.h>
#include <cmath>

#define N_NODES 50000
#define N_EDGES 800000
#define CAP 64                                /* per-node cap; Poisson(16) tail @64 ~1e-19 */

#define NBINS 196                             /* bin = dst >> 8 (256 nodes/bin) */
#define BIN_CAP 8192                          /* expected ~4096/bin */
#define CUR_PAD 32                            /* 1 cache line per bin cursor */

#define P1_EPT 16                             /* edges per thread (1024-thr blocks) */
#define P1_EPB (1024 * P1_EPT)                /* 16384 */
#define P1_BLOCKS ((N_EDGES + P1_EPB - 1) / P1_EPB)  /* 49: same-line atomic chain 391->49 */

#define HB_BLOCKS 98                          /* h->bf16: 100k threads x 16 f32 */
#define ELR_BLOCKS 196                        /* 3125 tiles / 16 waves */
#define WC_BLOCKS 30                          /* 30720 items / 1024 */
#define NB_HB  (P1_BLOCKS)                    /* 49 */
#define NB_ELR (NB_HB + HB_BLOCKS)            /* 147 */
#define NB_WC  (NB_ELR + ELR_BLOCKS)          /* 343 */
#define NB_WGB (NB_WC + WC_BLOCKS)            /* 373 */
#define PREP_TOTAL (NB_WGB + 1)               /* 374 */

#define AGGR_BLOCKS (N_NODES / 16)            /* 3125 */

typedef __attribute__((ext_vector_type(8))) short bf16x8;
typedef __attribute__((ext_vector_type(4))) float f32x4;

__device__ inline short bfbits(float x) {
    __hip_bfloat16 t = __float2bfloat16(x);
    return *reinterpret_cast<short*>(&t);
}
__device__ inline unsigned short bfu16(float x) {
    __hip_bfloat16 t = __float2bfloat16(x);
    return *reinterpret_cast<unsigned short*>(&t);
}

// ---------------------------------------------------------------------------
// K1 (fused partition + all prep), 1024 threads/block.
// [0,49): partition. R10: EPB=16384 -> 49 blocks. Device-scope same-address
//   atomics on bin_cursor serialize at the coherence point (~140 ns each);
//   chain depth per bin drops 391->49 (~55 us -> ~7 us predicted). Flush runs
//   lengthen to ~84 entries/bin (coalesced). Stage 64 KB LDS.
// [49,147): hb: h -> bf16 (3.2 MB gather table, fits per-XCD L2).
// [147,343): elr: el/er via one MFMA per 16-node tile.
// [343,373): Wc (GRU GEMM B). [373]: Wgb (projection B fragments).
// ---------------------------------------------------------------------------
__global__ __launch_bounds__(1024) void k_part_prep(
        const int* __restrict__ src, const int* __restrict__ dst,
        int* __restrict__ bin_cursor, unsigned* __restrict__ bin_buf,
        const float* __restrict__ h, const float* __restrict__ Wg,
        const float* __restrict__ al, const float* __restrict__ ar,
        const float* __restrict__ Wih, const float* __restrict__ Whh,
        unsigned short* __restrict__ hb, float* __restrict__ el,
        float* __restrict__ er, __hip_bfloat16* __restrict__ Wc,
        __hip_bfloat16* __restrict__ Wgb) {
    const int t = threadIdx.x;
    __shared__ union {
        struct {
            int bcnt[256], bofs[256], cur[256], gbase[256];
            int wt4[4];
            unsigned stage[P1_EPB];           // 64 KB
        } part;                               // ~68.1 KB
        __hip_bfloat16 vlr[16][32];           // 1 KB
    } sm;

    if (blockIdx.x < P1_BLOCKS) {
        // ---- partition role ----
        int* bcnt = sm.part.bcnt; int* bofs = sm.part.bofs;
        int* cur = sm.part.cur;   int* gbase = sm.part.gbase;
        int* wt4 = sm.part.wt4;   unsigned* stage = sm.part.stage;
        if (t < 256) bcnt[t] = 0;
        __syncthreads();
        int bn[P1_EPT];
        unsigned pk[P1_EPT];
        const int ebase = blockIdx.x * P1_EPB + t * P1_EPT;  // 800000%16==0: all-or-none
        if (ebase < N_EDGES) {
            int dd[P1_EPT], ss[P1_EPT];
#pragma unroll
            for (int q = 0; q < P1_EPT / 4; ++q) {
                *(int4*)(dd + q * 4) = *(const int4*)(dst + ebase + q * 4);
                *(int4*)(ss + q * 4) = *(const int4*)(src + ebase + q * 4);
            }
#pragma unroll
            for (int q = 0; q < P1_EPT; ++q) {
                bn[q] = dd[q] >> 8;
                pk[q] = (unsigned)ss[q] | ((unsigned)dd[q] << 16);
                atomicAdd(&bcnt[bn[q]], 1);
            }
        } else {
#pragma unroll
            for (int q = 0; q < P1_EPT; ++q) bn[q] = -1;
        }
        __syncthreads();
        int x = 0, vv = 0;
        if (t < 256) {
            vv = bcnt[t];
            x = vv;
            const int lane = t & 63;
#pragma unroll
            for (int m = 1; m < 64; m <<= 1) {
                const int y = __shfl_up(x, m, 64);
                if (lane >= m) x += y;
            }
            if (lane == 63) wt4[t >> 6] = x;
        }
        __syncthreads();
        if (t < 256) {
            const int wave4 = t >> 6;
            int wb = 0;
#pragma unroll
            for (int i = 0; i < 4; ++i) if (i < wave4) wb += wt4[i];
            const int off = wb + x - vv;
            bofs[t] = off;
            cur[t] = off;
            gbase[t] = (vv > 0) ? atomicAdd(&bin_cursor[t * CUR_PAD], vv) : 0;
        }
        __syncthreads();
        if (bn[0] >= 0) {
#pragma unroll
            for (int q = 0; q < P1_EPT; ++q)
                stage[atomicAdd(&cur[bn[q]], 1)] = pk[q];
        }
        __syncthreads();
        // coalesced cooperative flush
        const int tot = wt4[0] + wt4[1] + wt4[2] + wt4[3];
        for (int i = t; i < tot; i += 1024) {
            const unsigned e = stage[i];
            const int b = e >> 24;                 // dst>>8 (dst<2^16)
            const int gi = gbase[b] + (i - bofs[b]);
            if (gi < BIN_CAP) bin_buf[(size_t)b * BIN_CAP + gi] = e;
        }
        return;
    }
    if (blockIdx.x < NB_ELR) {
        // ---- hb role: h (f32) -> bf16 bits, 16 f32 per thread ----
        const int idx = (blockIdx.x - NB_HB) * 1024 + t;
        const int base = idx * 16;
        if (base < N_NODES * 32) {
            const float4* hp = (const float4*)(h + base);
            const float4 v0 = hp[0], v1 = hp[1], v2 = hp[2], v3 = hp[3];
            unsigned o[8];
            o[0] = (unsigned)bfu16(v0.x) | ((unsigned)bfu16(v0.y) << 16);
            o[1] = (unsigned)bfu16(v0.z) | ((unsigned)bfu16(v0.w) << 16);
            o[2] = (unsigned)bfu16(v1.x) | ((unsigned)bfu16(v1.y) << 16);
            o[3] = (unsigned)bfu16(v1.z) | ((unsigned)bfu16(v1.w) << 16);
            o[4] = (unsigned)bfu16(v2.x) | ((unsigned)bfu16(v2.y) << 16);
            o[5] = (unsigned)bfu16(v2.z) | ((unsigned)bfu16(v2.w) << 16);
            o[6] = (unsigned)bfu16(v3.x) | ((unsigned)bfu16(v3.y) << 16);
            o[7] = (unsigned)bfu16(v3.z) | ((unsigned)bfu16(v3.w) << 16);
            uint4* op = (uint4*)(hb + base);
            op[0] = (uint4){o[0], o[1], o[2], o[3]};
            op[1] = (uint4){o[4], o[5], o[6], o[7]};
        }
        return;
    }
    if (blockIdx.x < NB_WC) {
        // ---- elr role: el/er via MFMA, 16 waves x 16-node tiles ----
        if (t < 512) {
            const int col = t >> 5, k = t & 31;
            float v = 0.f;
            if (col < 8) {
                const int hd = col & 3;
                const float* a = (col < 4) ? (al + hd * 32) : (ar + hd * 32);
                const float* w = Wg + k * 128 + hd * 32;
#pragma unroll
                for (int f = 0; f < 32; ++f) v = fmaf(w[f], a[f], v);
            }
            sm.vlr[col][k] = __float2bfloat16(v);
        }
        __syncthreads();
        const int wave = t >> 6, lane = t & 63;
        const int li = lane & 15, quad = lane >> 4;
        const int mt = (blockIdx.x - NB_ELR) * 16 + wave;
        if (mt >= AGGR_BLOCKS) return;
        const int m_base = mt * 16;
        bf16x8 a;
        {
            const float4* hp = (const float4*)(h + (size_t)(m_base + li) * 32 + quad * 8);
            const float4 f0 = hp[0], f1 = hp[1];
            a[0] = bfbits(f0.x); a[1] = bfbits(f0.y); a[2] = bfbits(f0.z); a[3] = bfbits(f0.w);
            a[4] = bfbits(f1.x); a[5] = bfbits(f1.y); a[6] = bfbits(f1.z); a[7] = bfbits(f1.w);
        }
        const bf16x8 b = *(const bf16x8*)(&sm.vlr[li][0] + quad * 8);
        f32x4 acc = (f32x4){0.f, 0.f, 0.f, 0.f};
        acc = __builtin_amdgcn_mfma_f32_16x16x32_bf16(a, b, acc, 0, 0, 0);
        if (li < 8) {
#pragma unroll
            for (int i = 0; i < 4; ++i) {
                const int m = m_base + quad * 4 + i;
                if (li < 4) el[m * 4 + li] = acc[i];
                else        er[m * 4 + (li - 4)] = acc[i];
            }
        }
        return;
    }
    if (blockIdx.x < NB_WGB) {
        // ---- Wc role (GRU GEMM B, unchanged values) ----
        const int idx = (blockIdx.x - NB_WC) * 1024 + t;
        const int r = idx / 160, k = idx - r * 160;
        float v = 0.f;
        if (r < 96) { if (k < 128) v = Wih[r * 128 + k]; }
        else        { if (k >= 128) v = Whh[(r - 96) * 32 + (k - 128)]; }
        Wc[idx] = __float2bfloat16(v);
        return;
    }
    // ---- Wgb role: projection B, [h*32+f][k] ----
#pragma unroll
    for (int jj = 0; jj < 4; ++jj) {
        const int id = t * 4 + jj;             // 4096 items
        const int k = id & 31, f = (id >> 5) & 31, hd = id >> 10;
        Wgb[id] = __float2bfloat16(Wg[k * 128 + hd * 32 + f]);
    }
}

// ---------------------------------------------------------------------------
// K2 (aggr + project + GRU). Unchanged from R9 (bf16-h gather, commuted
// projection, fast-math epilogue) — kept byte-identical for attribution.
// ---------------------------------------------------------------------------
__global__ __launch_bounds__(256) void k_aggr_gru(
        const int* __restrict__ bin_cursor, const unsigned* __restrict__ bin_buf,
        const unsigned char* __restrict__ hb,
        const float* __restrict__ el, const float* __restrict__ er,
        const float* __restrict__ h, const __hip_bfloat16* __restrict__ Wc,
        const __hip_bfloat16* __restrict__ Wgb,
        const float* __restrict__ bih, const float* __restrict__ bhh,
        float* __restrict__ out) {
    __shared__ unsigned short list[16][CAP];      // 2 KB
    __shared__ int lcnt[16];
    __shared__ __hip_bfloat16 xh_tile[16][160];   // 5 KB
    __shared__ float eel_s[4][256];               // 4 KB
    __shared__ unsigned Sn[16][64];               // 4 KB: [row][h*16+dw] bf16x2
    __shared__ float ex[2][3][16][16];            // 6 KB gh exchange
    const int t = threadIdx.x;
    const int wave = t >> 6;
    const int lane = t & 63;
    const int pb = blockIdx.x >> 4, six = blockIdx.x & 15;
    const int mbase = blockIdx.x * 16;

    if (t < 16) lcnt[t] = 0;
    __syncthreads();

    // ---- stage A: filter parent bin into this block's 16 LDS lists ----
    const int cbn = min(bin_cursor[pb * CUR_PAD], BIN_CAP);
    const uint4* bb4 = (const uint4*)(bin_buf + (size_t)pb * BIN_CAP);
    for (int i = t * 4; i < cbn; i += 1024) {
        const uint4 p4 = bb4[i >> 2];
#pragma unroll
        for (int k = 0; k < 4; ++k) {
            if (i + k < cbn) {
                const unsigned p = (&p4.x)[k];
                const int local = (p >> 16) & 255;
                if ((local >> 4) == six) {
                    const int dl = local & 15;
                    const int pos = atomicAdd(&lcnt[dl], 1);
                    if (pos < CAP) list[dl][pos] = (unsigned short)(p & 0xffff);
                }
            }
        }
    }
    __syncthreads();

    // ---- phase 1: 4 nodes per wave; weights (eel) + bf16-h gather ----
    float* eel = eel_s[wave];
    const int hs = lane & 3;
    const int eq = lane >> 4;          // edge slot within round (0..3)
    const int dw = lane & 15;          // dword index in 64-B bf16 row
    for (int u = 0; u < 4; ++u) {
        const int row = wave * 4 + u;
        const int n = mbase + row;
        const float ern = er[n * 4 + hs];
        const int cnt = min(lcnt[row], CAP);
        const unsigned short* sl = list[row];
        // zero eel (stale from previous node; gather reads full rounds)
        eel[lane] = 0.f; eel[64 + lane] = 0.f;
        eel[128 + lane] = 0.f; eel[192 + lane] = 0.f;
        __builtin_amdgcn_wave_barrier();
        float psum = 0.f;
#pragma unroll
        for (int p = 0; p < 4; ++p) {
            const int j = p * 64 + lane;           // j&3 == lane&3
            if (j < cnt * 4) {
                const int s = sl[j >> 2];
                float v = el[s * 4 + hs] + ern;
                v = v > 0.f ? v : 0.2f * v;        // leaky_relu(0.2)
                const float e = __expf(v);
                eel[j] = e;
                psum += e;
            }
        }
        __builtin_amdgcn_wave_barrier();
        float a00 = 0.f, a01 = 0.f, a10 = 0.f, a11 = 0.f;
        float a20 = 0.f, a21 = 0.f, a30 = 0.f, a31 = 0.f;
        for (int i = 0; i < cnt; i += 16) {
            int e[4];
#pragma unroll
            for (int j = 0; j < 4; ++j) {
                const int ee = i + j * 4 + eq;
                e[j] = (ee < cnt) ? sl[ee] : 0;    // row 0 safe; weight is 0
            }
            unsigned q[4];
#pragma unroll
            for (int j = 0; j < 4; ++j)
                q[j] = *(const unsigned*)(hb + (size_t)e[j] * 64 + dw * 4);
#pragma unroll
            for (int j = 0; j < 4; ++j) {
                const int ee = i + j * 4 + eq;
                const float lo = __uint_as_float(q[j] << 16);
                const float hi = __uint_as_float(q[j] & 0xffff0000u);
                const float w0 = eel[ee * 4 + 0];
                const float w1 = eel[ee * 4 + 1];
                const float w2 = eel[ee * 4 + 2];
                const float w3 = eel[ee * 4 + 3];
                a00 = fmaf(w0, lo, a00); a01 = fmaf(w0, hi, a01);
                a10 = fmaf(w1, lo, a10); a11 = fmaf(w1, hi, a11);
                a20 = fmaf(w2, lo, a20); a21 = fmaf(w2, hi, a21);
                a30 = fmaf(w3, lo, a30); a31 = fmaf(w3, hi, a31);
            }
        }
        __builtin_amdgcn_wave_barrier();          // eel fully consumed
        // fold the 4 edge-slots (same dw, different eq)
#pragma unroll
        for (int m = 16; m < 64; m <<= 1) {
            a00 += __shfl_xor(a00, m, 64); a01 += __shfl_xor(a01, m, 64);
            a10 += __shfl_xor(a10, m, 64); a11 += __shfl_xor(a11, m, 64);
            a20 += __shfl_xor(a20, m, 64); a21 += __shfl_xor(a21, m, 64);
            a30 += __shfl_xor(a30, m, 64); a31 += __shfl_xor(a31, m, 64);
        }
        // psum: lane L holds head (L&3) total after masks 4..32
#pragma unroll
        for (int m = 4; m < 64; m <<= 1) psum += __shfl_xor(psum, m, 64);
        const float inv0 = (cnt > 0) ? 1.f / __shfl(psum, 0, 64) : 0.f;
        const float inv1 = (cnt > 0) ? 1.f / __shfl(psum, 1, 64) : 0.f;
        const float inv2 = (cnt > 0) ? 1.f / __shfl(psum, 2, 64) : 0.f;
        const float inv3 = (cnt > 0) ? 1.f / __shfl(psum, 3, 64) : 0.f;
        if (lane < 16) {                          // dw == lane: feats 2dw,2dw+1
            Sn[row][0 * 16 + lane] = (unsigned)bfu16(a00 * inv0) | ((unsigned)bfu16(a01 * inv0) << 16);
            Sn[row][1 * 16 + lane] = (unsigned)bfu16(a10 * inv1) | ((unsigned)bfu16(a11 * inv1) << 16);
            Sn[row][2 * 16 + lane] = (unsigned)bfu16(a20 * inv2) | ((unsigned)bfu16(a21 * inv2) << 16);
            Sn[row][3 * 16 + lane] = (unsigned)bfu16(a30 * inv3) | ((unsigned)bfu16(a31 * inv3) << 16);
        }
        if (lane < 32)
            xh_tile[row][128 + lane] = __float2bfloat16(h[(size_t)n * 32 + lane]);
    }
    __syncthreads();

    // ---- phase 1.5: projection MFMA, wave = head ----
    {
        const int li = lane & 15, quad = lane >> 4;
        const int head = wave;
        const __hip_bfloat16* snb = (const __hip_bfloat16*)&Sn[0][0]; // [16][128]
        const bf16x8 aS = *(const bf16x8*)(snb + li * 128 + head * 32 + quad * 8);
        const bf16x8 b0 = *(const bf16x8*)(Wgb + (size_t)(head * 32 + li) * 32 + quad * 8);
        const bf16x8 b1 = *(const bf16x8*)(Wgb + (size_t)(head * 32 + 16 + li) * 32 + quad * 8);
        f32x4 c0 = (f32x4){0.f, 0.f, 0.f, 0.f};
        f32x4 c1 = (f32x4){0.f, 0.f, 0.f, 0.f};
        c0 = __builtin_amdgcn_mfma_f32_16x16x32_bf16(aS, b0, c0, 0, 0, 0);
        c1 = __builtin_amdgcn_mfma_f32_16x16x32_bf16(aS, b1, c1, 0, 0, 0);
#pragma unroll
        for (int i = 0; i < 4; ++i) {
            const int row = quad * 4 + i;
            xh_tile[row][head * 32 + li]      = __float2bfloat16(c0[i]);
            xh_tile[row][head * 32 + 16 + li] = __float2bfloat16(c1[i]);
        }
    }
    __syncthreads();

    // ---- phase 2: GRU MFMA, 3 tiles per wave, gh exchange via LDS ----
    const int li = lane & 15, quad = lane >> 4;
    const int cb = wave >> 1;          // output col block
    const int ghrole = wave & 1;       // 0: gi tiles, 1: gh tiles
    bf16x8 a[5];
#pragma unroll
    for (int s = 0; s < 5; ++s)
        a[s] = *(const bf16x8*)((const char*)&xh_tile[0][0] + li * 320 + s * 64 + quad * 16);
    f32x4 acc[3];
#pragma unroll
    for (int g = 0; g < 3; ++g) {      // g: 0=r, 1=z, 2=n
        acc[g] = (f32x4){0.f, 0.f, 0.f, 0.f};
        const int j = g * 2 + cb + ghrole * 6;
        const bf16x8* bp = (const bf16x8*)(Wc + (size_t)(j * 16 + li) * 160 + quad * 8);
        acc[g] = __builtin_amdgcn_mfma_f32_16x16x32_bf16(a[0], bp[0],  acc[g], 0, 0, 0);
        acc[g] = __builtin_amdgcn_mfma_f32_16x16x32_bf16(a[1], bp[4],  acc[g], 0, 0, 0);
        acc[g] = __builtin_amdgcn_mfma_f32_16x16x32_bf16(a[2], bp[8],  acc[g], 0, 0, 0);
        acc[g] = __builtin_amdgcn_mfma_f32_16x16x32_bf16(a[3], bp[12], acc[g], 0, 0, 0);
        acc[g] = __builtin_amdgcn_mfma_f32_16x16x32_bf16(a[4], bp[16], acc[g], 0, 0, 0);
    }
    if (ghrole) {
#pragma unroll
        for (int g = 0; g < 3; ++g)
#pragma unroll
            for (int i = 0; i < 4; ++i)
                ex[cb][g][quad * 4 + i][li] = acc[g][i];
    }
    __syncthreads();
    if (!ghrole) {
        const int c = cb * 16 + li;
        const float bir = bih[c],      bhr = bhh[c];
        const float biz = bih[32 + c], bhz = bhh[32 + c];
        const float bin = bih[64 + c], bhn = bhh[64 + c];
#pragma unroll
        for (int i = 0; i < 4; ++i) {
            const int row = quad * 4 + i;
            const int m = mbase + row;
            const float gr = acc[0][i] + bir + ex[cb][0][row][li] + bhr;
            const float gz = acc[1][i] + biz + ex[cb][1][row][li] + bhz;
            const float r = 1.f / (1.f + __expf(-gr));
            const float z = 1.f / (1.f + __expf(-gz));
            const float tv = acc[2][i] + bin + r * (ex[cb][2][row][li] + bhn);
            const float em = __expf(-2.f * fabsf(tv));
            const float nn = copysignf((1.f - em) / (1.f + em), tv);
            const float hv = h[(size_t)m * 32 + c];
            const float hn = (1.f - z) * nn + z * hv;
            out[(size_t)m * 32 + c] = hn > 0.f ? hn : (__expf(hn) - 1.f);
        }
    }
}

extern "C" void kernel_launch(void* const* d_in, const int* in_sizes, int n_in,
                              void* d_out, int out_size, void* d_ws, size_t ws_size,
                              hipStream_t stream) {
    const float* h   = (const float*)d_in[0];
    const float* Wg  = (const float*)d_in[1];
    const float* al  = (const float*)d_in[2];
    const float* ar  = (const float*)d_in[3];
    const float* Wih = (const float*)d_in[4];
    const float* Whh = (const float*)d_in[5];
    const float* bih = (const float*)d_in[6];
    const float* bhh = (const float*)d_in[7];
    const int* src   = (const int*)d_in[8];
    const int* dst   = (const int*)d_in[9];
    float* out = (float*)d_out;

    // workspace layout (~11.4 MB). hb first: garbage-index reads (zero-weight
    // tail lanes) can reach hb + 4.2 MB, which lands inside bin_buf — safe.
    unsigned short* hb = (unsigned short*)d_ws;               // N*32 bf16 (3.2 MB)
    unsigned* bin_buf = (unsigned*)(hb + (size_t)N_NODES * 32); // NBINS*BIN_CAP (6.4 MB)
    float* el = (float*)(bin_buf + (size_t)NBINS * BIN_CAP);  // N*4 f32
    float* er = el + (size_t)N_NODES * 4;                     // N*4 f32
    __hip_bfloat16* Wc  = (__hip_bfloat16*)(er + (size_t)N_NODES * 4); // 30720 bf16
    __hip_bfloat16* Wgb = Wc + 30720;                         // 4096 bf16
    int* bin_cursor = (int*)(Wgb + 4096);                     // NBINS*CUR_PAD

    hipMemsetAsync(bin_cursor, 0, NBINS * CUR_PAD * sizeof(int), stream);
    k_part_prep<<<PREP_TOTAL, 1024, 0, stream>>>(
        src, dst, bin_cursor, bin_buf, h, Wg, al, ar, Wih, Whh,
        hb, el, er, Wc, Wgb);
    k_aggr_gru<<<AGGR_BLOCKS, 256, 0, stream>>>(
        bin_cursor, bin_buf, (const unsigned char*)hb, el, er, h, Wc, Wgb,
        bih, bhh, out);
}